// Round 1
// baseline (436.156 us; speedup 1.0000x reference)
//
#include <hip/hip_runtime.h>
#include <hip/hip_bf16.h>

typedef __attribute__((ext_vector_type(4))) float f32x4;
typedef __attribute__((ext_vector_type(8))) short s16x8;

__device__ __forceinline__ unsigned short f2bf(float f) {
    unsigned int u; __builtin_memcpy(&u, &f, 4);
    u += 0x7fffu + ((u >> 16) & 1u);
    return (unsigned short)(u >> 16);
}
__device__ __forceinline__ float bf2f(unsigned short h) {
    unsigned int u = ((unsigned int)h) << 16;
    float f; __builtin_memcpy(&f, &u, 4);
    return f;
}
__device__ __forceinline__ s16x8 pack8(f32x4 a, f32x4 b) {
    s16x8 r;
    r[0] = (short)f2bf(a[0]); r[1] = (short)f2bf(a[1]);
    r[2] = (short)f2bf(a[2]); r[3] = (short)f2bf(a[3]);
    r[4] = (short)f2bf(b[0]); r[5] = (short)f2bf(b[1]);
    r[6] = (short)f2bf(b[2]); r[7] = (short)f2bf(b[3]);
    return r;
}

// ---------------------------------------------------------------------------
// Generic C = A @ B^T (+bias) GEMM, K fixed = 256.
// A: [M][256] (row stride sA elems, batch stride bAstr), f32 or bf16.
// B: [N][256] (row stride sB), f32 or bf16.  C: [M][N] f32 or bf16.
// Block: 256 thr (4 waves), tile 128(M) x 64(N) per nt-iter, NT = N/64.
// A staged once (full K, 64KB LDS, XOR-swizzled), A-frags hoisted to regs.
// ---------------------------------------------------------------------------
template<bool AF32, bool BF32, bool OUTBF16, bool BIAS>
__global__ __launch_bounds__(256) void gemm_k256(
    const void* __restrict__ Ap, long sA, long bAstr,
    const void* __restrict__ Bp, long sB,
    const float* __restrict__ bias,
    void* __restrict__ Cp, long sC, long bCstr,
    int M, int N)
{
    __shared__ alignas(16) unsigned short As[128 * 256];
    __shared__ alignas(16) unsigned short Bs[64 * 256];
    const int tid = threadIdx.x;
    const int lane = tid & 63;
    const int w = tid >> 6;
    const int m0 = blockIdx.x * 128;
    const int z = blockIdx.z;

    // ---- stage A (128 rows x 256 k), global->bf16->LDS, swizzled ----
    {
        const int kk = (tid & 31) * 8;
        #pragma unroll
        for (int j = 0; j < 16; ++j) {
            const int row = (tid >> 5) + j * 8;
            int rowg = m0 + row; if (rowg > M - 1) rowg = M - 1;
            s16x8 v;
            if constexpr (AF32) {
                const float* s = (const float*)Ap + (size_t)z * bAstr + (size_t)rowg * sA + kk;
                f32x4 f0 = *(const f32x4*)s;
                f32x4 f1 = *(const f32x4*)(s + 4);
                v = pack8(f0, f1);
            } else {
                const unsigned short* s = (const unsigned short*)Ap + (size_t)z * bAstr + (size_t)rowg * sA + kk;
                v = *(const s16x8*)s;
            }
            *(s16x8*)((char*)As + row * 512 + ((kk * 2) ^ ((row & 7) << 4))) = v;
        }
    }
    __syncthreads();

    // ---- hoist A fragments to registers (whole K, this wave's 32 rows) ----
    s16x8 areg[8][2];
    #pragma unroll
    for (int ks = 0; ks < 8; ++ks) {
        const int kb = ks * 64 + ((lane >> 4) << 4);
        #pragma unroll
        for (int rf = 0; rf < 2; ++rf) {
            const int row = w * 32 + rf * 16 + (lane & 15);
            areg[ks][rf] = *(const s16x8*)((const char*)As + row * 512 + (kb ^ ((row & 7) << 4)));
        }
    }

    const int NT = N >> 6;
    for (int nt = 0; nt < NT; ++nt) {
        // ---- stage B tile (64 rows x 256 k) ----
        {
            const int kk = (tid & 31) * 8;
            #pragma unroll
            for (int j = 0; j < 8; ++j) {
                const int row = (tid >> 5) + j * 8;
                const int rowg = nt * 64 + row;
                s16x8 v;
                if constexpr (BF32) {
                    const float* s = (const float*)Bp + (size_t)rowg * sB + kk;
                    f32x4 f0 = *(const f32x4*)s;
                    f32x4 f1 = *(const f32x4*)(s + 4);
                    v = pack8(f0, f1);
                } else {
                    const unsigned short* s = (const unsigned short*)Bp + (size_t)rowg * sB + kk;
                    v = *(const s16x8*)s;
                }
                *(s16x8*)((char*)Bs + row * 512 + ((kk * 2) ^ ((row & 7) << 4))) = v;
            }
        }
        __syncthreads();

        f32x4 acc[2][4];
        const f32x4 zero = {0.f, 0.f, 0.f, 0.f};
        #pragma unroll
        for (int rf = 0; rf < 2; ++rf)
            #pragma unroll
            for (int cf = 0; cf < 4; ++cf)
                acc[rf][cf] = zero;

        #pragma unroll
        for (int ks = 0; ks < 8; ++ks) {
            const int kb = ks * 64 + ((lane >> 4) << 4);
            s16x8 bfr[4];
            #pragma unroll
            for (int cf = 0; cf < 4; ++cf) {
                const int row = cf * 16 + (lane & 15);
                bfr[cf] = *(const s16x8*)((const char*)Bs + row * 512 + (kb ^ ((row & 7) << 4)));
            }
            #pragma unroll
            for (int rf = 0; rf < 2; ++rf)
                #pragma unroll
                for (int cf = 0; cf < 4; ++cf)
                    acc[rf][cf] = __builtin_amdgcn_mfma_f32_16x16x32_bf16(
                        areg[ks][rf], bfr[cf], acc[rf][cf], 0, 0, 0);
        }

        // ---- epilogue ----
        #pragma unroll
        for (int cf = 0; cf < 4; ++cf) {
            const int n = nt * 64 + cf * 16 + (lane & 15);
            const float bv = BIAS ? bias[n] : 0.f;
            #pragma unroll
            for (int rf = 0; rf < 2; ++rf) {
                #pragma unroll
                for (int r = 0; r < 4; ++r) {
                    const int m = m0 + w * 32 + rf * 16 + ((lane >> 4) << 2) + r;
                    if (m < M) {
                        const float v = acc[rf][cf][r] + bv;
                        const size_t co = (size_t)z * bCstr + (size_t)m * sC + n;
                        if constexpr (OUTBF16) ((unsigned short*)Cp)[co] = f2bf(v);
                        else                   ((float*)Cp)[co] = v;
                    }
                }
            }
        }
        __syncthreads();
    }
}

// ---------------------------------------------------------------------------
// qa_b = bf16(q_agent * sc), ka_b = bf16(k_agent * sc);  sc = 1/16 folded in.
// ---------------------------------------------------------------------------
__global__ __launch_bounds__(256) void build_qa(const float* __restrict__ qa_out,
                                                unsigned short* __restrict__ qa_b,
                                                unsigned short* __restrict__ ka_b)
{
    const int a = blockIdx.x, k = threadIdx.x;
    qa_b[a * 256 + k] = f2bf(qa_out[(size_t)a * 512 + k] * 0.0625f);
    ka_b[a * 256 + k] = f2bf(qa_out[(size_t)a * 512 + 256 + k] * 0.0625f);
}

// ---------------------------------------------------------------------------
// Stage-1 softmax stats over n (8192) per (b,a):  partial max/sumexp per
// 512-token chunk, then combine.
// ---------------------------------------------------------------------------
__global__ __launch_bounds__(256) void s1_stats_part(const float* __restrict__ S1T,
                                                     float* __restrict__ mpart,
                                                     float* __restrict__ lpart)
{
    const int c = blockIdx.x, b = blockIdx.y;
    const int a = threadIdx.x & 63, s = threadIdx.x >> 6;
    const float* base = S1T + ((size_t)b * 8192 + c * 512 + s) * 64 + a;
    float mx = -1e30f;
    for (int i = 0; i < 128; ++i) mx = fmaxf(mx, base[(size_t)i * 256]);
    float sum = 0.f;
    for (int i = 0; i < 128; ++i) sum += __expf(base[(size_t)i * 256] - mx);
    __shared__ float ms[256], ls[256];
    ms[threadIdx.x] = mx; ls[threadIdx.x] = sum;
    __syncthreads();
    if (threadIdx.x < 64) {
        const int aa = threadIdx.x;
        float M = ms[aa];
        #pragma unroll
        for (int ss = 1; ss < 4; ++ss) M = fmaxf(M, ms[ss * 64 + aa]);
        float L = 0.f;
        #pragma unroll
        for (int ss = 0; ss < 4; ++ss) L += ls[ss * 64 + aa] * __expf(ms[ss * 64 + aa] - M);
        mpart[((size_t)b * 16 + c) * 64 + aa] = M;
        lpart[((size_t)b * 16 + c) * 64 + aa] = L;
    }
}

__global__ void s1_stats_combine(const float* __restrict__ mpart,
                                 const float* __restrict__ lpart,
                                 float* __restrict__ m1, float* __restrict__ l1inv)
{
    const int b = blockIdx.x, a = threadIdx.x; // 64 threads
    float M = -1e30f;
    for (int c = 0; c < 16; ++c) M = fmaxf(M, mpart[((size_t)b * 16 + c) * 64 + a]);
    float L = 0.f;
    for (int c = 0; c < 16; ++c) L += lpart[((size_t)b * 16 + c) * 64 + a] * __expf(mpart[((size_t)b * 16 + c) * 64 + a] - M);
    m1[b * 64 + a] = M;
    l1inv[b * 64 + a] = 1.0f / L;
}

// ---------------------------------------------------------------------------
// v1 partials: per (b, 256-token chunk) block computes, for all 64 agents,
// sum_n attn1[a][n] * v[n][d].  P staged in LDS (exp applied), broadcast read.
// ---------------------------------------------------------------------------
__global__ __launch_bounds__(256) void pv_partial(const float* __restrict__ S1T,
                                                  const unsigned short* __restrict__ qkv,
                                                  const float* __restrict__ m1,
                                                  const float* __restrict__ l1inv,
                                                  float* __restrict__ v1_part)
{
    __shared__ float P[256 * 64];
    const int tid = threadIdx.x;
    const int c = blockIdx.x, b = blockIdx.y;
    const int n0 = c * 256;
    {
        const int a = tid & 63, sl = tid >> 6;
        const float mA = m1[b * 64 + a];
        const float lA = l1inv[b * 64 + a];
        const float* src = S1T + ((size_t)b * 8192 + n0 + sl) * 64 + a;
        #pragma unroll 4
        for (int i = 0; i < 64; ++i) {
            P[(sl + 4 * i) * 64 + a] = __expf(src[(size_t)(4 * i) * 64] - mA) * lA;
        }
    }
    __syncthreads();
    const int d = tid;
    const f32x4 zero = {0.f, 0.f, 0.f, 0.f};
    f32x4 acc[16];
    #pragma unroll
    for (int i = 0; i < 16; ++i) acc[i] = zero;
    const unsigned short* vsrc = qkv + ((size_t)b * 8192 + n0) * 768 + 512 + d;
    for (int nl = 0; nl < 256; ++nl) {
        const float vv = bf2f(vsrc[(size_t)nl * 768]);
        const float* Pr = &P[nl * 64];
        #pragma unroll
        for (int i = 0; i < 16; ++i) {
            const f32x4 p4 = *(const f32x4*)(Pr + i * 4);
            acc[i] += p4 * vv;
        }
    }
    float* dst = v1_part + ((size_t)(b * 32 + c) * 64) * 256 + d;
    #pragma unroll
    for (int i = 0; i < 16; ++i)
        #pragma unroll
        for (int j = 0; j < 4; ++j)
            dst[(size_t)(i * 4 + j) * 256] = acc[i][j];
}

// reduce 32 chunks -> v1_raw[b][a][d]
__global__ __launch_bounds__(256) void v1_reduce(const float* __restrict__ v1_part,
                                                 float* __restrict__ v1_raw)
{
    const int a = blockIdx.x, b = blockIdx.y, d = threadIdx.x;
    float s = 0.f;
    for (int c = 0; c < 32; ++c)
        s += v1_part[(((size_t)b * 32 + c) * 64 + a) * 256 + d];
    v1_raw[((size_t)b * 64 + a) * 256 + d] = s;
}

// ---------------------------------------------------------------------------
// Stage-2 fused: softmax over 64 agents + PV against u (LDS) + residual +
// RMSNorm.  Wave per token (4 tokens pipelined per quad), block = 64 tokens.
// ---------------------------------------------------------------------------
__global__ __launch_bounds__(256) void stage2_final(const float* __restrict__ S2,
                                                    const float* __restrict__ u,
                                                    const float* __restrict__ x,
                                                    const float* __restrict__ nscale,
                                                    float* __restrict__ out)
{
    __shared__ float u_s[64 * 256];
    __shared__ float p_s[4][64][4];
    const int tid = threadIdx.x;
    const int b = blockIdx.x >> 7;                 // 128 blocks per batch
    const float* ub = u + (size_t)b * 64 * 256;
    #pragma unroll
    for (int i = 0; i < 16; ++i) {
        const int off = i * 1024 + tid * 4;
        *(f32x4*)&u_s[off] = *(const f32x4*)&ub[off];
    }
    __syncthreads();
    const int w = tid >> 6, lane = tid & 63;
    const f32x4 sc4 = *(const f32x4*)&nscale[lane * 4];
    const int tok0 = blockIdx.x * 64 + w * 16;
    const f32x4 zero = {0.f, 0.f, 0.f, 0.f};

    for (int q4 = 0; q4 < 4; ++q4) {
        const int n0 = tok0 + q4 * 4;
        #pragma unroll
        for (int g = 0; g < 4; ++g) {
            const int n = n0 + g;
            float s = S2[(size_t)n * 64 + lane];
            float mx = s;
            #pragma unroll
            for (int off = 32; off; off >>= 1) mx = fmaxf(mx, __shfl_xor(mx, off));
            float p = __expf(s - mx);
            float sm = p;
            #pragma unroll
            for (int off = 32; off; off >>= 1) sm += __shfl_xor(sm, off);
            p_s[w][lane][g] = p / sm;
        }
        f32x4 a0 = zero, a1 = zero, a2 = zero, a3 = zero;
        const float* ur = &u_s[lane * 4];
        #pragma unroll 8
        for (int a = 0; a < 64; ++a) {
            const f32x4 uv = *(const f32x4*)(ur + a * 256);
            const f32x4 pq = *(const f32x4*)&p_s[w][a][0];
            a0 += uv * pq[0];
            a1 += uv * pq[1];
            a2 += uv * pq[2];
            a3 += uv * pq[3];
        }
        #pragma unroll
        for (int g = 0; g < 4; ++g) {
            const int n = n0 + g;
            const f32x4 xr = *(const f32x4*)&x[(size_t)n * 256 + lane * 4];
            const f32x4 vg = (g == 0) ? a0 : (g == 1) ? a1 : (g == 2) ? a2 : a3;
            f32x4 y = vg + xr;
            float ss = y[0] * y[0] + y[1] * y[1] + y[2] * y[2] + y[3] * y[3];
            #pragma unroll
            for (int off = 32; off; off >>= 1) ss += __shfl_xor(ss, off);
            const float inv = 1.f / (sqrtf(ss) * 0.0625f + 1e-8f); // rms = ||y||/16
            f32x4 o = sc4 * y * inv;
            *(f32x4*)&out[(size_t)n * 256 + lane * 4] = o;
        }
    }
}

// ---------------------------------------------------------------------------
extern "C" void kernel_launch(void* const* d_in, const int* in_sizes, int n_in,
                              void* d_out, int out_size, void* d_ws, size_t ws_size,
                              hipStream_t stream)
{
    const float* agent   = (const float*)d_in[0];
    const float* x       = (const float*)d_in[1];
    const float* W_qkv   = (const float*)d_in[2];
    const float* b_qkv   = (const float*)d_in[3];
    const float* W_agent = (const float*)d_in[4];
    const float* b_agent = (const float*)d_in[5];
    const float* W_fc1   = (const float*)d_in[6];
    const float* b_fc1   = (const float*)d_in[7];
    const float* W_fc2   = (const float*)d_in[8];
    const float* b_fc2   = (const float*)d_in[9];
    const float* nscale  = (const float*)d_in[10];
    float* out = (float*)d_out;

    char* wsp = (char*)d_ws;
    size_t off = 0;
    auto alloc = [&](size_t n) { void* p = wsp + off; off += (n + 255) & ~(size_t)255; return p; };

    unsigned short* qkv   = (unsigned short*)alloc(65536UL * 768 * 2); // [65536][768] bf16: q|k|v
    float*  qa_out = (float*)alloc(64UL * 512 * 4);
    unsigned short* qa_b  = (unsigned short*)alloc(64UL * 256 * 2);
    unsigned short* ka_b  = (unsigned short*)alloc(64UL * 256 * 2);
    float*  S1T    = (float*)alloc(8UL * 8192 * 64 * 4);   // [b][n][a]
    float*  mpart  = (float*)alloc(8UL * 16 * 64 * 4);
    float*  lpart  = (float*)alloc(8UL * 16 * 64 * 4);
    float*  m1     = (float*)alloc(512UL * 4);
    float*  l1inv  = (float*)alloc(512UL * 4);
    float*  v1_part= (float*)alloc(8UL * 32 * 64 * 256 * 4);
    float*  v1_raw = (float*)alloc(512UL * 256 * 4);
    float*  t1     = (float*)alloc(512UL * 256 * 4);
    float*  uu     = (float*)alloc(512UL * 256 * 4);
    float*  S2     = (float*)alloc(65536UL * 64 * 4);

    // 1. qkv projection: [65536][768] bf16
    gemm_k256<true, true, true, true><<<dim3(512, 1, 1), 256, 0, stream>>>(
        x, 256, 0, W_qkv, 256, b_qkv, qkv, 768, 0, 65536, 768);
    // 2. agent projection: [64][512] f32
    gemm_k256<true, true, false, true><<<dim3(1, 1, 1), 256, 0, stream>>>(
        agent, 256, 0, W_agent, 256, b_agent, qa_out, 512, 0, 64, 512);
    // 3. scale (1/16) + bf16 cast of q_agent / k_agent
    build_qa<<<64, 256, 0, stream>>>(qa_out, qa_b, ka_b);
    // 4. stage-1 scores S1T[b][n][a] = k[b][n] . qa_scaled[a]
    gemm_k256<false, false, false, false><<<dim3(64, 1, 8), 256, 0, stream>>>(
        qkv + 256, 768, 8192L * 768, qa_b, 256, nullptr, S1T, 64, 8192L * 64, 8192, 64);
    // 5/6. softmax stats over n
    s1_stats_part<<<dim3(16, 8), 256, 0, stream>>>(S1T, mpart, lpart);
    s1_stats_combine<<<8, 64, 0, stream>>>(mpart, lpart, m1, l1inv);
    // 7. v1 partial accumulation
    pv_partial<<<dim3(32, 8), 256, 0, stream>>>(S1T, qkv, m1, l1inv, v1_part);
    // 8. reduce partials
    v1_reduce<<<dim3(64, 8), 256, 0, stream>>>(v1_part, v1_raw);
    // 9/10. fc1 then folded fc2: u = (v1@W_fc1^T + b1)@W_fc2^T + b2
    gemm_k256<true, true, false, true><<<dim3(4, 1, 1), 256, 0, stream>>>(
        v1_raw, 256, 0, W_fc1, 256, b_fc1, t1, 256, 0, 512, 256);
    gemm_k256<true, true, false, true><<<dim3(4, 1, 1), 256, 0, stream>>>(
        t1, 256, 0, W_fc2, 256, b_fc2, uu, 256, 0, 512, 256);
    // 11. stage-2 scores S2[n][a] = q[n] . ka_scaled[a]
    gemm_k256<false, false, false, false><<<dim3(512, 1, 1), 256, 0, stream>>>(
        qkv, 768, 0, ka_b, 256, nullptr, S2, 64, 0, 65536, 64);
    // 12. softmax(64) + PV(u) + residual + rmsnorm
    stage2_final<<<1024, 256, 0, stream>>>(S2, uu, x, nscale, out);
}

// Round 2
// 286.885 us; speedup vs baseline: 1.5203x; 1.5203x over previous
//
#include <hip/hip_runtime.h>
#include <hip/hip_bf16.h>

typedef __attribute__((ext_vector_type(4))) float f32x4;
typedef __attribute__((ext_vector_type(8))) short s16x8;

__device__ __forceinline__ unsigned short f2bf(float f) {
    unsigned int u; __builtin_memcpy(&u, &f, 4);
    u += 0x7fffu + ((u >> 16) & 1u);
    return (unsigned short)(u >> 16);
}
__device__ __forceinline__ float bf2f(unsigned short h) {
    unsigned int u = ((unsigned int)h) << 16;
    float f; __builtin_memcpy(&f, &u, 4);
    return f;
}
__device__ __forceinline__ s16x8 pack8(f32x4 a, f32x4 b) {
    s16x8 r;
    r[0] = (short)f2bf(a[0]); r[1] = (short)f2bf(a[1]);
    r[2] = (short)f2bf(a[2]); r[3] = (short)f2bf(a[3]);
    r[4] = (short)f2bf(b[0]); r[5] = (short)f2bf(b[1]);
    r[6] = (short)f2bf(b[2]); r[7] = (short)f2bf(b[3]);
    return r;
}

// ---------------------------------------------------------------------------
// Generic C = A @ B^T (+bias) GEMM, K=256 — used only for SMALL matmuls
// (agent projection, fc1, fc2).
// ---------------------------------------------------------------------------
template<bool AF32, bool BF32, bool OUTBF16, bool BIAS>
__global__ __launch_bounds__(256) void gemm_k256(
    const void* __restrict__ Ap, long sA, long bAstr,
    const void* __restrict__ Bp, long sB,
    const float* __restrict__ bias,
    void* __restrict__ Cp, long sC, long bCstr,
    int M, int N)
{
    __shared__ alignas(16) unsigned short As[128 * 256];
    __shared__ alignas(16) unsigned short Bs[64 * 256];
    const int tid = threadIdx.x;
    const int lane = tid & 63;
    const int w = tid >> 6;
    const int m0 = blockIdx.x * 128;
    const int z = blockIdx.z;

    {
        const int kk = (tid & 31) * 8;
        #pragma unroll
        for (int j = 0; j < 16; ++j) {
            const int row = (tid >> 5) + j * 8;
            int rowg = m0 + row; if (rowg > M - 1) rowg = M - 1;
            s16x8 v;
            if constexpr (AF32) {
                const float* s = (const float*)Ap + (size_t)z * bAstr + (size_t)rowg * sA + kk;
                f32x4 f0 = *(const f32x4*)s;
                f32x4 f1 = *(const f32x4*)(s + 4);
                v = pack8(f0, f1);
            } else {
                const unsigned short* s = (const unsigned short*)Ap + (size_t)z * bAstr + (size_t)rowg * sA + kk;
                v = *(const s16x8*)s;
            }
            *(s16x8*)((char*)As + row * 512 + ((kk * 2) ^ ((row & 7) << 4))) = v;
        }
    }
    __syncthreads();

    s16x8 areg[8][2];
    #pragma unroll
    for (int ks = 0; ks < 8; ++ks) {
        const int kb = ks * 64 + ((lane >> 4) << 4);
        #pragma unroll
        for (int rf = 0; rf < 2; ++rf) {
            const int row = w * 32 + rf * 16 + (lane & 15);
            areg[ks][rf] = *(const s16x8*)((const char*)As + row * 512 + (kb ^ ((row & 7) << 4)));
        }
    }

    const int NT = N >> 6;
    for (int nt = 0; nt < NT; ++nt) {
        {
            const int kk = (tid & 31) * 8;
            #pragma unroll
            for (int j = 0; j < 8; ++j) {
                const int row = (tid >> 5) + j * 8;
                const int rowg = nt * 64 + row;
                s16x8 v;
                if constexpr (BF32) {
                    const float* s = (const float*)Bp + (size_t)rowg * sB + kk;
                    f32x4 f0 = *(const f32x4*)s;
                    f32x4 f1 = *(const f32x4*)(s + 4);
                    v = pack8(f0, f1);
                } else {
                    const unsigned short* s = (const unsigned short*)Bp + (size_t)rowg * sB + kk;
                    v = *(const s16x8*)s;
                }
                *(s16x8*)((char*)Bs + row * 512 + ((kk * 2) ^ ((row & 7) << 4))) = v;
            }
        }
        __syncthreads();

        f32x4 acc[2][4];
        const f32x4 zero = {0.f, 0.f, 0.f, 0.f};
        #pragma unroll
        for (int rf = 0; rf < 2; ++rf)
            #pragma unroll
            for (int cf = 0; cf < 4; ++cf)
                acc[rf][cf] = zero;

        #pragma unroll
        for (int ks = 0; ks < 8; ++ks) {
            const int kb = ks * 64 + ((lane >> 4) << 4);
            s16x8 bfr[4];
            #pragma unroll
            for (int cf = 0; cf < 4; ++cf) {
                const int row = cf * 16 + (lane & 15);
                bfr[cf] = *(const s16x8*)((const char*)Bs + row * 512 + (kb ^ ((row & 7) << 4)));
            }
            #pragma unroll
            for (int rf = 0; rf < 2; ++rf)
                #pragma unroll
                for (int cf = 0; cf < 4; ++cf)
                    acc[rf][cf] = __builtin_amdgcn_mfma_f32_16x16x32_bf16(
                        areg[ks][rf], bfr[cf], acc[rf][cf], 0, 0, 0);
        }

        #pragma unroll
        for (int cf = 0; cf < 4; ++cf) {
            const int n = nt * 64 + cf * 16 + (lane & 15);
            const float bv = BIAS ? bias[n] : 0.f;
            #pragma unroll
            for (int rf = 0; rf < 2; ++rf) {
                #pragma unroll
                for (int r = 0; r < 4; ++r) {
                    const int m = m0 + w * 32 + rf * 16 + ((lane >> 4) << 2) + r;
                    if (m < M) {
                        const float v = acc[rf][cf][r] + bv;
                        const size_t co = (size_t)z * bCstr + (size_t)m * sC + n;
                        if constexpr (OUTBF16) ((unsigned short*)Cp)[co] = f2bf(v);
                        else                   ((float*)Cp)[co] = v;
                    }
                }
            }
        }
        __syncthreads();
    }
}

// ---------------------------------------------------------------------------
// Build combined B matrix [384][256] bf16 and bias [384]:
//   rows   0..255 : W_v rows            (bias = b_v)
//   rows 256..319 : M1[a] = qa_s @ W_k  (bias = b_k . qa_s[a])
//   rows 320..383 : M2[a] = ka_s @ W_q  (bias = b_q . ka_s[a])
// qa_s/ka_s = (agent proj rows) * 1/16 (softmax scale folded).
// ---------------------------------------------------------------------------
__global__ __launch_bounds__(256) void build_M(
    const float* __restrict__ W_qkv, const float* __restrict__ b_qkv,
    const float* __restrict__ qa_out, // [64][512]: q_agent | k_agent
    unsigned short* __restrict__ Bcomb, float* __restrict__ bcomb)
{
    const int i = blockIdx.x;  // 0..383
    const int t = threadIdx.x;
    if (i < 256) {
        Bcomb[i * 256 + t] = f2bf(W_qkv[(size_t)(512 + i) * 256 + t]);
        if (t == 0) bcomb[i] = b_qkv[512 + i];
        return;
    }
    __shared__ float qs[256];
    const int a = (i - 256) & 63;
    const bool isS1 = (i < 320);
    qs[t] = qa_out[(size_t)a * 512 + (isS1 ? t : 256 + t)] * 0.0625f;
    __syncthreads();
    const float* W  = W_qkv + (isS1 ? 256 * 256 : 0);   // W_k : W_q
    const float* bb = b_qkv + (isS1 ? 256 : 0);
    float acc = 0.f, cb = 0.f;
    for (int dout = 0; dout < 256; ++dout) {
        const float q = qs[dout];
        acc += q * W[(size_t)dout * 256 + t];
        cb  += q * bb[dout];
    }
    Bcomb[i * 256 + t] = f2bf(acc);
    if (t == 0) bcomb[i] = cb;
}

// ---------------------------------------------------------------------------
// Fused streaming GEMM over x: out cols = [ v(256, bf16) | S1(64, f32) |
// S2(64, f32) ].  64-row tiles, 4 waves (wave w owns col-tiles c == w mod 4).
// A staged in 32KB swizzled LDS; B frags read from L2-resident bf16 Bcomb.
// Also emits per-block stage-1 softmax partials (max / sumexp over 64 rows).
// ---------------------------------------------------------------------------
__global__ __launch_bounds__(256) void xproj(
    const float* __restrict__ x,
    const unsigned short* __restrict__ Bcomb,
    const float* __restrict__ bcomb,
    unsigned short* __restrict__ vout,
    float* __restrict__ S1T,
    float* __restrict__ S2,
    float* __restrict__ mpart, float* __restrict__ lpart)
{
    __shared__ alignas(16) unsigned short As[64 * 256];
    const int tid = threadIdx.x, lane = tid & 63, w = tid >> 6;
    const int lr = lane & 15, lq = lane >> 4;
    const long m0 = (long)blockIdx.x * 64;

    // stage A (64 x 256 f32 -> bf16 LDS, XOR swizzled)
    {
        const int k0 = (tid & 31) * 8;
        #pragma unroll
        for (int j = 0; j < 8; ++j) {
            const int row = (tid >> 5) + j * 8;
            const float* s = x + (m0 + row) * 256 + k0;
            f32x4 f0 = *(const f32x4*)s;
            f32x4 f1 = *(const f32x4*)(s + 4);
            *(s16x8*)((char*)As + row * 512 + ((k0 * 2) ^ ((row & 7) << 4))) = pack8(f0, f1);
        }
    }
    __syncthreads();

    f32x4 acc[4][6];
    const f32x4 zero = {0.f, 0.f, 0.f, 0.f};
    #pragma unroll
    for (int rf = 0; rf < 4; ++rf)
        #pragma unroll
        for (int j = 0; j < 6; ++j)
            acc[rf][j] = zero;

    #pragma unroll
    for (int ks = 0; ks < 8; ++ks) {
        const int kb = ks * 64 + lq * 16;  // byte offset within 512-B row
        s16x8 areg[4];
        #pragma unroll
        for (int rf = 0; rf < 4; ++rf) {
            const int row = rf * 16 + lr;
            areg[rf] = *(const s16x8*)((const char*)As + row * 512 + (kb ^ ((row & 7) << 4)));
        }
        s16x8 bfr[6];
        #pragma unroll
        for (int j = 0; j < 6; ++j) {
            const int col = (w + 4 * j) * 16 + lr;
            bfr[j] = *(const s16x8*)((const char*)Bcomb + (size_t)col * 512 + kb);
        }
        #pragma unroll
        for (int rf = 0; rf < 4; ++rf)
            #pragma unroll
            for (int j = 0; j < 6; ++j)
                acc[rf][j] = __builtin_amdgcn_mfma_f32_16x16x32_bf16(
                    areg[rf], bfr[j], acc[rf][j], 0, 0, 0);
    }

    // epilogue
    #pragma unroll
    for (int j = 0; j < 6; ++j) {
        const int c = w + 4 * j;
        const float bv = bcomb[c * 16 + lr];
        if (c < 16) {
            // v region: bf16
            #pragma unroll
            for (int rf = 0; rf < 4; ++rf)
                #pragma unroll
                for (int r = 0; r < 4; ++r) {
                    const long m = m0 + rf * 16 + lq * 4 + r;
                    vout[m * 256 + c * 16 + lr] = f2bf(acc[rf][j][r] + bv);
                }
        } else {
            float* dst = (c < 20) ? S1T : S2;
            const int a = (c < 20) ? (c - 16) * 16 + lr : (c - 20) * 16 + lr;
            float mx = -1e30f;
            #pragma unroll
            for (int rf = 0; rf < 4; ++rf)
                #pragma unroll
                for (int r = 0; r < 4; ++r) {
                    const float v = acc[rf][j][r] + bv;
                    dst[(m0 + rf * 16 + lq * 4 + r) * 64 + a] = v;
                    mx = fmaxf(mx, v);
                }
            if (c < 20) {
                mx = fmaxf(mx, __shfl_xor(mx, 16));
                mx = fmaxf(mx, __shfl_xor(mx, 32));
                float sm = 0.f;
                #pragma unroll
                for (int rf = 0; rf < 4; ++rf)
                    #pragma unroll
                    for (int r = 0; r < 4; ++r)
                        sm += __expf(acc[rf][j][r] + bv - mx);
                sm += __shfl_xor(sm, 16);
                sm += __shfl_xor(sm, 32);
                if (lq == 0) {
                    mpart[(size_t)blockIdx.x * 64 + a] = mx;
                    lpart[(size_t)blockIdx.x * 64 + a] = sm;
                }
            }
        }
    }
}

// ---------------------------------------------------------------------------
// Combine per-64-token-chunk stage-1 partials (128 chunks per batch).
// ---------------------------------------------------------------------------
__global__ __launch_bounds__(256) void s1_combine(const float* __restrict__ mpart,
                                                  const float* __restrict__ lpart,
                                                  float* __restrict__ m1,
                                                  float* __restrict__ l1inv)
{
    const int b = blockIdx.x;
    const int a = threadIdx.x & 63, s = threadIdx.x >> 6;
    float M = -1e30f;
    for (int c = s; c < 128; c += 4)
        M = fmaxf(M, mpart[((size_t)b * 128 + c) * 64 + a]);
    float L = 0.f;
    for (int c = s; c < 128; c += 4) {
        const size_t idx = ((size_t)b * 128 + c) * 64 + a;
        L += lpart[idx] * __expf(mpart[idx] - M);
    }
    __shared__ float ms[256], ls[256];
    ms[threadIdx.x] = M; ls[threadIdx.x] = L;
    __syncthreads();
    if (threadIdx.x < 64) {
        const int aa = threadIdx.x;
        float Mm = ms[aa];
        #pragma unroll
        for (int ss = 1; ss < 4; ++ss) Mm = fmaxf(Mm, ms[ss * 64 + aa]);
        float Ll = 0.f;
        #pragma unroll
        for (int ss = 0; ss < 4; ++ss) Ll += ls[ss * 64 + aa] * __expf(ms[ss * 64 + aa] - Mm);
        m1[b * 64 + aa] = Mm;
        l1inv[b * 64 + aa] = 1.0f / Ll;
    }
}

// ---------------------------------------------------------------------------
// v1 partials: per (b, 256-token chunk): for all 64 agents,
// sum_n attn1[a][n] * v[n][d].  P staged in LDS, broadcast read.
// ---------------------------------------------------------------------------
__global__ __launch_bounds__(256) void pv_partial(const float* __restrict__ S1T,
                                                  const unsigned short* __restrict__ vout,
                                                  const float* __restrict__ m1,
                                                  const float* __restrict__ l1inv,
                                                  float* __restrict__ v1_part)
{
    __shared__ float P[256 * 64];
    const int tid = threadIdx.x;
    const int c = blockIdx.x, b = blockIdx.y;
    const int n0 = c * 256;
    {
        const int a = tid & 63, sl = tid >> 6;
        const float mA = m1[b * 64 + a];
        const float lA = l1inv[b * 64 + a];
        const float* src = S1T + ((size_t)b * 8192 + n0 + sl) * 64 + a;
        #pragma unroll 4
        for (int i = 0; i < 64; ++i) {
            P[(sl + 4 * i) * 64 + a] = __expf(src[(size_t)(4 * i) * 64] - mA) * lA;
        }
    }
    __syncthreads();
    const int d = tid;
    const f32x4 zero = {0.f, 0.f, 0.f, 0.f};
    f32x4 acc[16];
    #pragma unroll
    for (int i = 0; i < 16; ++i) acc[i] = zero;
    const unsigned short* vsrc = vout + ((size_t)b * 8192 + n0) * 256 + d;
    for (int nl = 0; nl < 256; ++nl) {
        const float vv = bf2f(vsrc[(size_t)nl * 256]);
        const float* Pr = &P[nl * 64];
        #pragma unroll
        for (int i = 0; i < 16; ++i) {
            const f32x4 p4 = *(const f32x4*)(Pr + i * 4);
            acc[i] += p4 * vv;
        }
    }
    float* dst = v1_part + ((size_t)(b * 32 + c) * 64) * 256 + d;
    #pragma unroll
    for (int i = 0; i < 16; ++i)
        #pragma unroll
        for (int j = 0; j < 4; ++j)
            dst[(size_t)(i * 4 + j) * 256] = acc[i][j];
}

__global__ __launch_bounds__(256) void v1_reduce(const float* __restrict__ v1_part,
                                                 float* __restrict__ v1_raw)
{
    const int a = blockIdx.x, b = blockIdx.y, d = threadIdx.x;
    float s = 0.f;
    for (int c = 0; c < 32; ++c)
        s += v1_part[(((size_t)b * 32 + c) * 64 + a) * 256 + d];
    v1_raw[((size_t)b * 64 + a) * 256 + d] = s;
}

// ---------------------------------------------------------------------------
// Stage-2 fused: softmax(64) + PV against u (LDS) + residual + RMSNorm.
// ---------------------------------------------------------------------------
__global__ __launch_bounds__(256) void stage2_final(const float* __restrict__ S2,
                                                    const float* __restrict__ u,
                                                    const float* __restrict__ x,
                                                    const float* __restrict__ nscale,
                                                    float* __restrict__ out)
{
    __shared__ float u_s[64 * 256];
    __shared__ float p_s[4][64][4];
    const int tid = threadIdx.x;
    const int b = blockIdx.x >> 7;
    const float* ub = u + (size_t)b * 64 * 256;
    #pragma unroll
    for (int i = 0; i < 16; ++i) {
        const int off = i * 1024 + tid * 4;
        *(f32x4*)&u_s[off] = *(const f32x4*)&ub[off];
    }
    __syncthreads();
    const int w = tid >> 6, lane = tid & 63;
    const f32x4 sc4 = *(const f32x4*)&nscale[lane * 4];
    const int tok0 = blockIdx.x * 64 + w * 16;
    const f32x4 zero = {0.f, 0.f, 0.f, 0.f};

    for (int q4 = 0; q4 < 4; ++q4) {
        const int n0 = tok0 + q4 * 4;
        #pragma unroll
        for (int g = 0; g < 4; ++g) {
            const int n = n0 + g;
            float s = S2[(size_t)n * 64 + lane];
            float mx = s;
            #pragma unroll
            for (int off = 32; off; off >>= 1) mx = fmaxf(mx, __shfl_xor(mx, off));
            float p = __expf(s - mx);
            float sm = p;
            #pragma unroll
            for (int off = 32; off; off >>= 1) sm += __shfl_xor(sm, off);
            p_s[w][lane][g] = p / sm;
        }
        f32x4 a0 = zero, a1 = zero, a2 = zero, a3 = zero;
        const float* ur = &u_s[lane * 4];
        #pragma unroll 8
        for (int a = 0; a < 64; ++a) {
            const f32x4 uv = *(const f32x4*)(ur + a * 256);
            const f32x4 pq = *(const f32x4*)&p_s[w][a][0];
            a0 += uv * pq[0];
            a1 += uv * pq[1];
            a2 += uv * pq[2];
            a3 += uv * pq[3];
        }
        #pragma unroll
        for (int g = 0; g < 4; ++g) {
            const int n = n0 + g;
            const f32x4 xr = *(const f32x4*)&x[(size_t)n * 256 + lane * 4];
            const f32x4 vg = (g == 0) ? a0 : (g == 1) ? a1 : (g == 2) ? a2 : a3;
            f32x4 y = vg + xr;
            float ss = y[0] * y[0] + y[1] * y[1] + y[2] * y[2] + y[3] * y[3];
            #pragma unroll
            for (int off = 32; off; off >>= 1) ss += __shfl_xor(ss, off);
            const float inv = 1.f / (sqrtf(ss) * 0.0625f + 1e-8f);
            f32x4 o = sc4 * y * inv;
            *(f32x4*)&out[(size_t)n * 256 + lane * 4] = o;
        }
    }
}

// ---------------------------------------------------------------------------
extern "C" void kernel_launch(void* const* d_in, const int* in_sizes, int n_in,
                              void* d_out, int out_size, void* d_ws, size_t ws_size,
                              hipStream_t stream)
{
    const float* agent   = (const float*)d_in[0];
    const float* x       = (const float*)d_in[1];
    const float* W_qkv   = (const float*)d_in[2];
    const float* b_qkv   = (const float*)d_in[3];
    const float* W_agent = (const float*)d_in[4];
    const float* b_agent = (const float*)d_in[5];
    const float* W_fc1   = (const float*)d_in[6];
    const float* b_fc1   = (const float*)d_in[7];
    const float* W_fc2   = (const float*)d_in[8];
    const float* b_fc2   = (const float*)d_in[9];
    const float* nscale  = (const float*)d_in[10];
    float* out = (float*)d_out;

    char* wsp = (char*)d_ws;
    size_t off = 0;
    auto alloc = [&](size_t n) { void* p = wsp + off; off += (n + 255) & ~(size_t)255; return p; };

    float*  qa_out = (float*)alloc(64UL * 512 * 4);
    unsigned short* Bcomb = (unsigned short*)alloc(384UL * 256 * 2);
    float*  bcomb  = (float*)alloc(384UL * 4);
    unsigned short* vout  = (unsigned short*)alloc(65536UL * 256 * 2);
    float*  S1T    = (float*)alloc(65536UL * 64 * 4);
    float*  S2     = (float*)alloc(65536UL * 64 * 4);
    float*  mpart  = (float*)alloc(1024UL * 64 * 4);
    float*  lpart  = (float*)alloc(1024UL * 64 * 4);
    float*  m1     = (float*)alloc(512UL * 4);
    float*  l1inv  = (float*)alloc(512UL * 4);
    float*  v1_part= (float*)alloc(8UL * 32 * 64 * 256 * 4);
    float*  v1_raw = (float*)alloc(512UL * 256 * 4);
    float*  t1     = (float*)alloc(512UL * 256 * 4);
    float*  uu     = (float*)alloc(512UL * 256 * 4);

    // 1. agent projection: [64][512] f32
    gemm_k256<true, true, false, true><<<dim3(1, 1, 1), 256, 0, stream>>>(
        agent, 256, 0, W_agent, 256, b_agent, qa_out, 512, 0, 64, 512);
    // 2. combined B matrix (W_v | qa_s@W_k | ka_s@W_q) + bias consts
    build_M<<<384, 256, 0, stream>>>(W_qkv, b_qkv, qa_out, Bcomb, bcomb);
    // 3. fused streaming GEMM: v, S1, S2 + stage-1 softmax partials
    xproj<<<1024, 256, 0, stream>>>(x, Bcomb, bcomb, vout, S1T, S2, mpart, lpart);
    // 4. combine stage-1 stats
    s1_combine<<<8, 256, 0, stream>>>(mpart, lpart, m1, l1inv);
    // 5. v1 partial accumulation
    pv_partial<<<dim3(32, 8), 256, 0, stream>>>(S1T, vout, m1, l1inv, v1_part);
    // 6. reduce partials
    v1_reduce<<<dim3(64, 8), 256, 0, stream>>>(v1_part, v1_raw);
    // 7/8. fc1 then folded fc2 (softmax rows sum to 1): u = (v1@W1^T+b1)@W2^T+b2
    gemm_k256<true, true, false, true><<<dim3(4, 1, 1), 256, 0, stream>>>(
        v1_raw, 256, 0, W_fc1, 256, b_fc1, t1, 256, 0, 512, 256);
    gemm_k256<true, true, false, true><<<dim3(4, 1, 1), 256, 0, stream>>>(
        t1, 256, 0, W_fc2, 256, b_fc2, uu, 256, 0, 512, 256);
    // 9. softmax(64) + PV(u) + residual + rmsnorm
    stage2_final<<<1024, 256, 0, stream>>>(S2, uu, x, nscale, out);
}

// Round 3
// 240.617 us; speedup vs baseline: 1.8127x; 1.1923x over previous
//
#include <hip/hip_runtime.h>
#include <hip/hip_bf16.h>

typedef __attribute__((ext_vector_type(4))) float f32x4;
typedef __attribute__((ext_vector_type(8))) short s16x8;
typedef __attribute__((ext_vector_type(4))) short s16x4;

__device__ __forceinline__ unsigned short f2bf(float f) {
    unsigned int u; __builtin_memcpy(&u, &f, 4);
    u += 0x7fffu + ((u >> 16) & 1u);
    return (unsigned short)(u >> 16);
}
__device__ __forceinline__ float bf2f(unsigned short h) {
    unsigned int u = ((unsigned int)h) << 16;
    float f; __builtin_memcpy(&f, &u, 4);
    return f;
}
__device__ __forceinline__ s16x8 pack8(f32x4 a, f32x4 b) {
    s16x8 r;
    r[0] = (short)f2bf(a[0]); r[1] = (short)f2bf(a[1]);
    r[2] = (short)f2bf(a[2]); r[3] = (short)f2bf(a[3]);
    r[4] = (short)f2bf(b[0]); r[5] = (short)f2bf(b[1]);
    r[6] = (short)f2bf(b[2]); r[7] = (short)f2bf(b[3]);
    return r;
}

// ---------------------------------------------------------------------------
// Generic C = A @ B^T (+bias) GEMM, K=256 — small matmuls only (agent proj,
// fc1, fc2).
// ---------------------------------------------------------------------------
template<bool AF32, bool BF32, bool OUTBF16, bool BIAS>
__global__ __launch_bounds__(256) void gemm_k256(
    const void* __restrict__ Ap, long sA, long bAstr,
    const void* __restrict__ Bp, long sB,
    const float* __restrict__ bias,
    void* __restrict__ Cp, long sC, long bCstr,
    int M, int N)
{
    __shared__ alignas(16) unsigned short As[128 * 256];
    __shared__ alignas(16) unsigned short Bs[64 * 256];
    const int tid = threadIdx.x;
    const int lane = tid & 63;
    const int w = tid >> 6;
    const int m0 = blockIdx.x * 128;
    const int z = blockIdx.z;

    {
        const int kk = (tid & 31) * 8;
        #pragma unroll
        for (int j = 0; j < 16; ++j) {
            const int row = (tid >> 5) + j * 8;
            int rowg = m0 + row; if (rowg > M - 1) rowg = M - 1;
            s16x8 v;
            if constexpr (AF32) {
                const float* s = (const float*)Ap + (size_t)z * bAstr + (size_t)rowg * sA + kk;
                f32x4 f0 = *(const f32x4*)s;
                f32x4 f1 = *(const f32x4*)(s + 4);
                v = pack8(f0, f1);
            } else {
                const unsigned short* s = (const unsigned short*)Ap + (size_t)z * bAstr + (size_t)rowg * sA + kk;
                v = *(const s16x8*)s;
            }
            *(s16x8*)((char*)As + row * 512 + ((kk * 2) ^ ((row & 7) << 4))) = v;
        }
    }
    __syncthreads();

    s16x8 areg[8][2];
    #pragma unroll
    for (int ks = 0; ks < 8; ++ks) {
        const int kb = ks * 64 + ((lane >> 4) << 4);
        #pragma unroll
        for (int rf = 0; rf < 2; ++rf) {
            const int row = w * 32 + rf * 16 + (lane & 15);
            areg[ks][rf] = *(const s16x8*)((const char*)As + row * 512 + (kb ^ ((row & 7) << 4)));
        }
    }

    const int NT = N >> 6;
    for (int nt = 0; nt < NT; ++nt) {
        {
            const int kk = (tid & 31) * 8;
            #pragma unroll
            for (int j = 0; j < 8; ++j) {
                const int row = (tid >> 5) + j * 8;
                const int rowg = nt * 64 + row;
                s16x8 v;
                if constexpr (BF32) {
                    const float* s = (const float*)Bp + (size_t)rowg * sB + kk;
                    f32x4 f0 = *(const f32x4*)s;
                    f32x4 f1 = *(const f32x4*)(s + 4);
                    v = pack8(f0, f1);
                } else {
                    const unsigned short* s = (const unsigned short*)Bp + (size_t)rowg * sB + kk;
                    v = *(const s16x8*)s;
                }
                *(s16x8*)((char*)Bs + row * 512 + ((kk * 2) ^ ((row & 7) << 4))) = v;
            }
        }
        __syncthreads();

        f32x4 acc[2][4];
        const f32x4 zero = {0.f, 0.f, 0.f, 0.f};
        #pragma unroll
        for (int rf = 0; rf < 2; ++rf)
            #pragma unroll
            for (int cf = 0; cf < 4; ++cf)
                acc[rf][cf] = zero;

        #pragma unroll
        for (int ks = 0; ks < 8; ++ks) {
            const int kb = ks * 64 + ((lane >> 4) << 4);
            s16x8 bfr[4];
            #pragma unroll
            for (int cf = 0; cf < 4; ++cf) {
                const int row = cf * 16 + (lane & 15);
                bfr[cf] = *(const s16x8*)((const char*)Bs + row * 512 + (kb ^ ((row & 7) << 4)));
            }
            #pragma unroll
            for (int rf = 0; rf < 2; ++rf)
                #pragma unroll
                for (int cf = 0; cf < 4; ++cf)
                    acc[rf][cf] = __builtin_amdgcn_mfma_f32_16x16x32_bf16(
                        areg[ks][rf], bfr[cf], acc[rf][cf], 0, 0, 0);
        }

        #pragma unroll
        for (int cf = 0; cf < 4; ++cf) {
            const int n = nt * 64 + cf * 16 + (lane & 15);
            const float bv = BIAS ? bias[n] : 0.f;
            #pragma unroll
            for (int rf = 0; rf < 2; ++rf) {
                #pragma unroll
                for (int r = 0; r < 4; ++r) {
                    const int m = m0 + w * 32 + rf * 16 + ((lane >> 4) << 2) + r;
                    if (m < M) {
                        const float v = acc[rf][cf][r] + bv;
                        const size_t co = (size_t)z * bCstr + (size_t)m * sC + n;
                        if constexpr (OUTBF16) ((unsigned short*)Cp)[co] = f2bf(v);
                        else                   ((float*)Cp)[co] = v;
                    }
                }
            }
        }
        __syncthreads();
    }
}

// ---------------------------------------------------------------------------
// Build combined B matrix [384][256] bf16 and bias [384]:
//   rows   0..255 : W_v rows            (bias = b_v)
//   rows 256..319 : M1[a] = qa_s @ W_k  (bias = b_k . qa_s[a])
//   rows 320..383 : M2[a] = ka_s @ W_q  (bias = b_q . ka_s[a])
// ---------------------------------------------------------------------------
__global__ __launch_bounds__(256) void build_M(
    const float* __restrict__ W_qkv, const float* __restrict__ b_qkv,
    const float* __restrict__ qa_out,
    unsigned short* __restrict__ Bcomb, float* __restrict__ bcomb)
{
    const int i = blockIdx.x;
    const int t = threadIdx.x;
    if (i < 256) {
        Bcomb[i * 256 + t] = f2bf(W_qkv[(size_t)(512 + i) * 256 + t]);
        if (t == 0) bcomb[i] = b_qkv[512 + i];
        return;
    }
    __shared__ float qs[256];
    const int a = (i - 256) & 63;
    const bool isS1 = (i < 320);
    qs[t] = qa_out[(size_t)a * 512 + (isS1 ? t : 256 + t)] * 0.0625f;
    __syncthreads();
    const float* W  = W_qkv + (isS1 ? 256 * 256 : 0);
    const float* bb = b_qkv + (isS1 ? 256 : 0);
    float acc = 0.f, cb = 0.f;
    for (int dout = 0; dout < 256; ++dout) {
        const float q = qs[dout];
        acc += q * W[(size_t)dout * 256 + t];
        cb  += q * bb[dout];
    }
    Bcomb[i * 256 + t] = f2bf(acc);
    if (t == 0) bcomb[i] = cb;
}

// ---------------------------------------------------------------------------
// Fused streaming GEMM over x.  Per 64-token block, cols = [v(256) | S1(64) |
// S2(64)].  v written TRANSPOSED to vT[256 d][65536 n] (bf16) via LDS
// transpose (reusing As); S1T[n][a] f32; S2[n][a] f32; stage-1 partial stats.
// ---------------------------------------------------------------------------
__global__ __launch_bounds__(256) void xproj(
    const float* __restrict__ x,
    const unsigned short* __restrict__ Bcomb,
    const float* __restrict__ bcomb,
    unsigned short* __restrict__ vT,
    float* __restrict__ S1T,
    float* __restrict__ S2,
    float* __restrict__ mpart, float* __restrict__ lpart)
{
    __shared__ alignas(16) unsigned short As[64 * 256];   // 32KB; reused as [256 d][64 n]
    const int tid = threadIdx.x, lane = tid & 63, w = tid >> 6;
    const int lr = lane & 15, lq = lane >> 4;
    const long m0 = (long)blockIdx.x * 64;

    // stage A (64 x 256 f32 -> bf16 LDS, XOR swizzled)
    {
        const int k0 = (tid & 31) * 8;
        #pragma unroll
        for (int j = 0; j < 8; ++j) {
            const int row = (tid >> 5) + j * 8;
            const float* s = x + (m0 + row) * 256 + k0;
            f32x4 f0 = *(const f32x4*)s;
            f32x4 f1 = *(const f32x4*)(s + 4);
            *(s16x8*)((char*)As + row * 512 + ((k0 * 2) ^ ((row & 7) << 4))) = pack8(f0, f1);
        }
    }
    __syncthreads();

    f32x4 acc[4][6];
    const f32x4 zero = {0.f, 0.f, 0.f, 0.f};
    #pragma unroll
    for (int rf = 0; rf < 4; ++rf)
        #pragma unroll
        for (int j = 0; j < 6; ++j)
            acc[rf][j] = zero;

    #pragma unroll
    for (int ks = 0; ks < 8; ++ks) {
        const int kb = ks * 64 + lq * 16;
        s16x8 areg[4];
        #pragma unroll
        for (int rf = 0; rf < 4; ++rf) {
            const int row = rf * 16 + lr;
            areg[rf] = *(const s16x8*)((const char*)As + row * 512 + (kb ^ ((row & 7) << 4)));
        }
        s16x8 bfr[6];
        #pragma unroll
        for (int j = 0; j < 6; ++j) {
            const int col = (w + 4 * j) * 16 + lr;
            bfr[j] = *(const s16x8*)((const char*)Bcomb + (size_t)col * 512 + kb);
        }
        #pragma unroll
        for (int rf = 0; rf < 4; ++rf)
            #pragma unroll
            for (int j = 0; j < 6; ++j)
                acc[rf][j] = __builtin_amdgcn_mfma_f32_16x16x32_bf16(
                    areg[rf], bfr[j], acc[rf][j], 0, 0, 0);
    }
    __syncthreads();   // As dead; reuse as transpose buffer

    // ---- v cols (j=0..3): bf16 into As as [256 d][64 n], swizzled ----
    #pragma unroll
    for (int j = 0; j < 4; ++j) {
        const int c = w + 4 * j;
        const int d = c * 16 + lr;
        const float bv = bcomb[d];
        #pragma unroll
        for (int rf = 0; rf < 4; ++rf) {
            s16x4 pk;
            #pragma unroll
            for (int r = 0; r < 4; ++r) pk[r] = (short)f2bf(acc[rf][j][r] + bv);
            *(s16x4*)((char*)As + d * 128 + ((rf * 32 + lq * 8) ^ ((d & 7) << 4))) = pk;
        }
    }

    // ---- S1 (j=4) and S2 (j=5): direct global, + stage-1 partial stats ----
    #pragma unroll
    for (int j = 4; j < 6; ++j) {
        const int cIdx = (j == 4) ? (16 + w) : (20 + w);
        const float bv = bcomb[cIdx * 16 + lr];
        float* dst = (j == 4) ? S1T : S2;
        const int a = w * 16 + lr;
        float mx = -1e30f;
        #pragma unroll
        for (int rf = 0; rf < 4; ++rf)
            #pragma unroll
            for (int r = 0; r < 4; ++r) {
                const float v = acc[rf][j][r] + bv;
                dst[(m0 + rf * 16 + lq * 4 + r) * 64 + a] = v;
                mx = fmaxf(mx, v);
            }
        if (j == 4) {
            mx = fmaxf(mx, __shfl_xor(mx, 16));
            mx = fmaxf(mx, __shfl_xor(mx, 32));
            float sm = 0.f;
            #pragma unroll
            for (int rf = 0; rf < 4; ++rf)
                #pragma unroll
                for (int r = 0; r < 4; ++r)
                    sm += __expf(acc[rf][j][r] + bv - mx);
            sm += __shfl_xor(sm, 16);
            sm += __shfl_xor(sm, 32);
            if (lq == 0) {
                mpart[(size_t)blockIdx.x * 64 + a] = mx;
                lpart[(size_t)blockIdx.x * 64 + a] = sm;
            }
        }
    }
    __syncthreads();

    // ---- readout transpose buffer -> vT global ----
    #pragma unroll
    for (int i = 0; i < 8; ++i) {
        const int d = i * 32 + (tid >> 3);
        const int sub = tid & 7;
        s16x8 vv = *(const s16x8*)((const char*)As + d * 128 + ((sub * 16) ^ ((d & 7) << 4)));
        *(s16x8*)(vT + (size_t)d * 65536 + m0 + sub * 8) = vv;
    }
}

// ---------------------------------------------------------------------------
// Combine stage-1 partials (128 chunks of 64 tokens per batch).
// ---------------------------------------------------------------------------
__global__ __launch_bounds__(256) void s1_combine(const float* __restrict__ mpart,
                                                  const float* __restrict__ lpart,
                                                  float* __restrict__ m1,
                                                  float* __restrict__ l1inv)
{
    const int b = blockIdx.x;
    const int a = threadIdx.x & 63, s = threadIdx.x >> 6;
    float M = -1e30f;
    for (int c = s; c < 128; c += 4)
        M = fmaxf(M, mpart[((size_t)b * 128 + c) * 64 + a]);
    float L = 0.f;
    for (int c = s; c < 128; c += 4) {
        const size_t idx = ((size_t)b * 128 + c) * 64 + a;
        L += lpart[idx] * __expf(mpart[idx] - M);
    }
    __shared__ float ms[256], ls[256];
    ms[threadIdx.x] = M; ls[threadIdx.x] = L;
    __syncthreads();
    if (threadIdx.x < 64) {
        const int aa = threadIdx.x;
        float Mm = ms[aa];
        #pragma unroll
        for (int ss = 1; ss < 4; ++ss) Mm = fmaxf(Mm, ms[ss * 64 + aa]);
        float Ll = 0.f;
        #pragma unroll
        for (int ss = 0; ss < 4; ++ss) Ll += ls[ss * 64 + aa] * __expf(ms[ss * 64 + aa] - Mm);
        m1[b * 64 + aa] = Mm;
        l1inv[b * 64 + aa] = 1.0f / Ll;
    }
}

// ---------------------------------------------------------------------------
// PV via MFMA: v1_part[b][c][64 a][256 d] = P(chunk) @ V(chunk)^T with
// P[a][n] = exp(S1-m1)*l1inv (bf16, LDS-transposed from S1T[n][a]) and
// V[d][n] from vT (already k-contiguous).  Block: (c=32 n-chunks of 256,
// dh=2 d-halves, b=8).  K-tiles of 128, 48KB LDS.
// ---------------------------------------------------------------------------
__global__ __launch_bounds__(256) void pv_mfma(
    const float* __restrict__ S1T,
    const unsigned short* __restrict__ vT,
    const float* __restrict__ m1,
    const float* __restrict__ l1inv,
    float* __restrict__ v1_part)
{
    __shared__ alignas(16) unsigned short P_lds[64 * 128];   // [a][n] 16KB
    __shared__ alignas(16) unsigned short V_lds[128 * 128];  // [d][n] 32KB
    const int tid = threadIdx.x, lane = tid & 63, w = tid >> 6;
    const int lr = lane & 15, lq = lane >> 4;
    const int c = blockIdx.x, dh = blockIdx.y, b = blockIdx.z;

    const int a4 = (tid & 15) * 4;
    const f32x4 m4 = *(const f32x4*)&m1[b * 64 + a4];
    const f32x4 l4 = *(const f32x4*)&l1inv[b * 64 + a4];

    f32x4 acc[4][2];
    const f32x4 zero = {0.f, 0.f, 0.f, 0.f};
    #pragma unroll
    for (int rf = 0; rf < 4; ++rf)
        #pragma unroll
        for (int cf = 0; cf < 2; ++cf)
            acc[rf][cf] = zero;

    for (int kt = 0; kt < 2; ++kt) {
        const size_t ng0 = (size_t)b * 8192 + c * 256 + kt * 128;
        // ---- P stage: S1T[n][a] f32 -> exp -> bf16 P_lds[a][n] ----
        #pragma unroll
        for (int pass = 0; pass < 4; ++pass) {
            const int np = 2 * (tid >> 4) + pass * 32;
            const float* s = S1T + (ng0 + np) * 64 + a4;
            f32x4 s0 = *(const f32x4*)s;
            f32x4 s1 = *(const f32x4*)(s + 64);
            #pragma unroll
            for (int j = 0; j < 4; ++j) {
                const int a = a4 + j;
                const float p0 = __expf(s0[j] - m4[j]) * l4[j];
                const float p1 = __expf(s1[j] - m4[j]) * l4[j];
                const unsigned int pk = (unsigned int)f2bf(p0) | ((unsigned int)f2bf(p1) << 16);
                *(unsigned int*)((char*)P_lds + a * 256 + ((np * 2) ^ (((a >> 1) & 7) << 4))) = pk;
            }
        }
        // ---- V stage: vT rows (n-contiguous) -> V_lds[d][n] ----
        {
            const int chunk = tid & 15, dbase = tid >> 4;
            #pragma unroll
            for (int i = 0; i < 8; ++i) {
                const int d = dbase + i * 16;
                s16x8 vv = *(const s16x8*)(vT + (size_t)(dh * 128 + d) * 65536 + ng0 + chunk * 8);
                *(s16x8*)((char*)V_lds + d * 256 + ((chunk * 16) ^ ((d & 7) << 4))) = vv;
            }
        }
        __syncthreads();
        #pragma unroll
        for (int ks = 0; ks < 4; ++ks) {
            const int kb = ks * 64 + lq * 16;
            s16x8 af[4], bfv[2];
            #pragma unroll
            for (int rf = 0; rf < 4; ++rf) {
                const int row = rf * 16 + lr;
                af[rf] = *(const s16x8*)((const char*)P_lds + row * 256 + (kb ^ (((row >> 1) & 7) << 4)));
            }
            #pragma unroll
            for (int cf = 0; cf < 2; ++cf) {
                const int dr = w * 32 + cf * 16 + lr;
                bfv[cf] = *(const s16x8*)((const char*)V_lds + dr * 256 + (kb ^ ((dr & 7) << 4)));
            }
            #pragma unroll
            for (int rf = 0; rf < 4; ++rf)
                #pragma unroll
                for (int cf = 0; cf < 2; ++cf)
                    acc[rf][cf] = __builtin_amdgcn_mfma_f32_16x16x32_bf16(
                        af[rf], bfv[cf], acc[rf][cf], 0, 0, 0);
        }
        __syncthreads();
    }
    #pragma unroll
    for (int rf = 0; rf < 4; ++rf)
        #pragma unroll
        for (int cf = 0; cf < 2; ++cf)
            #pragma unroll
            for (int r = 0; r < 4; ++r) {
                const int a = rf * 16 + lq * 4 + r;
                const int d = dh * 128 + w * 32 + cf * 16 + lr;
                v1_part[(((size_t)b * 32 + c) * 64 + a) * 256 + d] = acc[rf][cf][r];
            }
}

__global__ void v1_reduce(const float* __restrict__ v1_part,
                          float* __restrict__ v1_raw)
{
    const int a = blockIdx.x, b = blockIdx.y, t = threadIdx.x;  // 64 thr
    f32x4 s = {0.f, 0.f, 0.f, 0.f};
    for (int c = 0; c < 32; ++c)
        s += *(const f32x4*)&v1_part[(((size_t)b * 32 + c) * 64 + a) * 256 + t * 4];
    *(f32x4*)&v1_raw[((size_t)b * 64 + a) * 256 + t * 4] = s;
}

// ---------------------------------------------------------------------------
// Stage-2 fused: softmax(64) + PV against u (LDS) + residual + RMSNorm.
// ---------------------------------------------------------------------------
__global__ __launch_bounds__(256) void stage2_final(const float* __restrict__ S2,
                                                    const float* __restrict__ u,
                                                    const float* __restrict__ x,
                                                    const float* __restrict__ nscale,
                                                    float* __restrict__ out)
{
    __shared__ float u_s[64 * 256];
    __shared__ float p_s[4][64][4];
    const int tid = threadIdx.x;
    const int b = blockIdx.x >> 7;
    const float* ub = u + (size_t)b * 64 * 256;
    #pragma unroll
    for (int i = 0; i < 16; ++i) {
        const int off = i * 1024 + tid * 4;
        *(f32x4*)&u_s[off] = *(const f32x4*)&ub[off];
    }
    __syncthreads();
    const int w = tid >> 6, lane = tid & 63;
    const f32x4 sc4 = *(const f32x4*)&nscale[lane * 4];
    const int tok0 = blockIdx.x * 64 + w * 16;
    const f32x4 zero = {0.f, 0.f, 0.f, 0.f};

    for (int q4 = 0; q4 < 4; ++q4) {
        const int n0 = tok0 + q4 * 4;
        #pragma unroll
        for (int g = 0; g < 4; ++g) {
            const int n = n0 + g;
            float s = S2[(size_t)n * 64 + lane];
            float mx = s;
            #pragma unroll
            for (int off = 32; off; off >>= 1) mx = fmaxf(mx, __shfl_xor(mx, off));
            float p = __expf(s - mx);
            float sm = p;
            #pragma unroll
            for (int off = 32; off; off >>= 1) sm += __shfl_xor(sm, off);
            p_s[w][lane][g] = p / sm;
        }
        f32x4 a0 = zero, a1 = zero, a2 = zero, a3 = zero;
        const float* ur = &u_s[lane * 4];
        #pragma unroll 8
        for (int a = 0; a < 64; ++a) {
            const f32x4 uv = *(const f32x4*)(ur + a * 256);
            const f32x4 pq = *(const f32x4*)&p_s[w][a][0];
            a0 += uv * pq[0];
            a1 += uv * pq[1];
            a2 += uv * pq[2];
            a3 += uv * pq[3];
        }
        #pragma unroll
        for (int g = 0; g < 4; ++g) {
            const int n = n0 + g;
            const f32x4 xr = *(const f32x4*)&x[(size_t)n * 256 + lane * 4];
            const f32x4 vg = (g == 0) ? a0 : (g == 1) ? a1 : (g == 2) ? a2 : a3;
            f32x4 y = vg + xr;
            float ss = y[0] * y[0] + y[1] * y[1] + y[2] * y[2] + y[3] * y[3];
            #pragma unroll
            for (int off = 32; off; off >>= 1) ss += __shfl_xor(ss, off);
            const float inv = 1.f / (sqrtf(ss) * 0.0625f + 1e-8f);
            f32x4 o = sc4 * y * inv;
            *(f32x4*)&out[(size_t)n * 256 + lane * 4] = o;
        }
    }
}

// ---------------------------------------------------------------------------
extern "C" void kernel_launch(void* const* d_in, const int* in_sizes, int n_in,
                              void* d_out, int out_size, void* d_ws, size_t ws_size,
                              hipStream_t stream)
{
    const float* agent   = (const float*)d_in[0];
    const float* x       = (const float*)d_in[1];
    const float* W_qkv   = (const float*)d_in[2];
    const float* b_qkv   = (const float*)d_in[3];
    const float* W_agent = (const float*)d_in[4];
    const float* b_agent = (const float*)d_in[5];
    const float* W_fc1   = (const float*)d_in[6];
    const float* b_fc1   = (const float*)d_in[7];
    const float* W_fc2   = (const float*)d_in[8];
    const float* b_fc2   = (const float*)d_in[9];
    const float* nscale  = (const float*)d_in[10];
    float* out = (float*)d_out;

    char* wsp = (char*)d_ws;
    size_t off = 0;
    auto alloc = [&](size_t n) { void* p = wsp + off; off += (n + 255) & ~(size_t)255; return p; };

    float*  qa_out = (float*)alloc(64UL * 512 * 4);
    unsigned short* Bcomb = (unsigned short*)alloc(384UL * 256 * 2);
    float*  bcomb  = (float*)alloc(384UL * 4);
    unsigned short* vT = (unsigned short*)alloc(256UL * 65536 * 2);  // [d][n] bf16
    float*  S1T    = (float*)alloc(65536UL * 64 * 4);                // [n][a]
    float*  S2     = (float*)alloc(65536UL * 64 * 4);                // [n][a]
    float*  mpart  = (float*)alloc(1024UL * 64 * 4);
    float*  lpart  = (float*)alloc(1024UL * 64 * 4);
    float*  m1     = (float*)alloc(512UL * 4);
    float*  l1inv  = (float*)alloc(512UL * 4);
    float*  v1_part= (float*)alloc(8UL * 32 * 64 * 256 * 4);
    float*  v1_raw = (float*)alloc(512UL * 256 * 4);
    float*  t1     = (float*)alloc(512UL * 256 * 4);
    float*  uu     = (float*)alloc(512UL * 256 * 4);

    // 1. agent projection
    gemm_k256<true, true, false, true><<<dim3(1, 1, 1), 256, 0, stream>>>(
        agent, 256, 0, W_agent, 256, b_agent, qa_out, 512, 0, 64, 512);
    // 2. combined B matrix
    build_M<<<384, 256, 0, stream>>>(W_qkv, b_qkv, qa_out, Bcomb, bcomb);
    // 3. fused streaming GEMM: vT (transposed), S1, S2, stage-1 partials
    xproj<<<1024, 256, 0, stream>>>(x, Bcomb, bcomb, vT, S1T, S2, mpart, lpart);
    // 4. combine stage-1 stats
    s1_combine<<<8, 256, 0, stream>>>(mpart, lpart, m1, l1inv);
    // 5. PV via MFMA (partials over 32 n-chunks)
    pv_mfma<<<dim3(32, 2, 8), 256, 0, stream>>>(S1T, vT, m1, l1inv, v1_part);
    // 6. reduce partials
    v1_reduce<<<dim3(64, 8), 64, 0, stream>>>(v1_part, v1_raw);
    // 7/8. fc1 then folded fc2: u = (v1@W1^T+b1)@W2^T+b2
    gemm_k256<true, true, false, true><<<dim3(4, 1, 1), 256, 0, stream>>>(
        v1_raw, 256, 0, W_fc1, 256, b_fc1, t1, 256, 0, 512, 256);
    gemm_k256<true, true, false, true><<<dim3(4, 1, 1), 256, 0, stream>>>(
        t1, 256, 0, W_fc2, 256, b_fc2, uu, 256, 0, 512, 256);
    // 9. softmax(64) + PV(u) + residual + rmsnorm
    stage2_final<<<1024, 256, 0, stream>>>(S2, uu, x, nscale, out);
}

// Round 4
// 240.044 us; speedup vs baseline: 1.8170x; 1.0024x over previous
//
#include <hip/hip_runtime.h>
#include <hip/hip_bf16.h>

typedef __attribute__((ext_vector_type(4))) float f32x4;
typedef __attribute__((ext_vector_type(8))) short s16x8;
typedef __attribute__((ext_vector_type(4))) short s16x4;

__device__ __forceinline__ unsigned short f2bf(float f) {
    unsigned int u; __builtin_memcpy(&u, &f, 4);
    u += 0x7fffu + ((u >> 16) & 1u);
    return (unsigned short)(u >> 16);
}
__device__ __forceinline__ float bf2f(unsigned short h) {
    unsigned int u = ((unsigned int)h) << 16;
    float f; __builtin_memcpy(&f, &u, 4);
    return f;
}
__device__ __forceinline__ s16x8 pack8(f32x4 a, f32x4 b) {
    s16x8 r;
    r[0] = (short)f2bf(a[0]); r[1] = (short)f2bf(a[1]);
    r[2] = (short)f2bf(a[2]); r[3] = (short)f2bf(a[3]);
    r[4] = (short)f2bf(b[0]); r[5] = (short)f2bf(b[1]);
    r[6] = (short)f2bf(b[2]); r[7] = (short)f2bf(b[3]);
    return r;
}

// ---------------------------------------------------------------------------
// Generic C = A @ B^T (+bias) GEMM, K=256 — small matmuls (agent proj, chain).
// ---------------------------------------------------------------------------
template<bool AF32, bool BF32, bool OUTBF16, bool BIAS>
__global__ __launch_bounds__(256) void gemm_k256(
    const void* __restrict__ Ap, long sA, long bAstr,
    const void* __restrict__ Bp, long sB,
    const float* __restrict__ bias,
    void* __restrict__ Cp, long sC, long bCstr,
    int M, int N)
{
    __shared__ alignas(16) unsigned short As[128 * 256];
    __shared__ alignas(16) unsigned short Bs[64 * 256];
    const int tid = threadIdx.x;
    const int lane = tid & 63;
    const int w = tid >> 6;
    const int m0 = blockIdx.x * 128;
    const int z = blockIdx.z;

    {
        const int kk = (tid & 31) * 8;
        #pragma unroll
        for (int j = 0; j < 16; ++j) {
            const int row = (tid >> 5) + j * 8;
            int rowg = m0 + row; if (rowg > M - 1) rowg = M - 1;
            s16x8 v;
            if constexpr (AF32) {
                const float* s = (const float*)Ap + (size_t)z * bAstr + (size_t)rowg * sA + kk;
                f32x4 f0 = *(const f32x4*)s;
                f32x4 f1 = *(const f32x4*)(s + 4);
                v = pack8(f0, f1);
            } else {
                const unsigned short* s = (const unsigned short*)Ap + (size_t)z * bAstr + (size_t)rowg * sA + kk;
                v = *(const s16x8*)s;
            }
            *(s16x8*)((char*)As + row * 512 + ((kk * 2) ^ ((row & 7) << 4))) = v;
        }
    }
    __syncthreads();

    s16x8 areg[8][2];
    #pragma unroll
    for (int ks = 0; ks < 8; ++ks) {
        const int kb = ks * 64 + ((lane >> 4) << 4);
        #pragma unroll
        for (int rf = 0; rf < 2; ++rf) {
            const int row = w * 32 + rf * 16 + (lane & 15);
            areg[ks][rf] = *(const s16x8*)((const char*)As + row * 512 + (kb ^ ((row & 7) << 4)));
        }
    }

    const int NT = N >> 6;
    for (int nt = 0; nt < NT; ++nt) {
        {
            const int kk = (tid & 31) * 8;
            #pragma unroll
            for (int j = 0; j < 8; ++j) {
                const int row = (tid >> 5) + j * 8;
                const int rowg = nt * 64 + row;
                s16x8 v;
                if constexpr (BF32) {
                    const float* s = (const float*)Bp + (size_t)rowg * sB + kk;
                    f32x4 f0 = *(const f32x4*)s;
                    f32x4 f1 = *(const f32x4*)(s + 4);
                    v = pack8(f0, f1);
                } else {
                    const unsigned short* s = (const unsigned short*)Bp + (size_t)rowg * sB + kk;
                    v = *(const s16x8*)s;
                }
                *(s16x8*)((char*)Bs + row * 512 + ((kk * 2) ^ ((row & 7) << 4))) = v;
            }
        }
        __syncthreads();

        f32x4 acc[2][4];
        const f32x4 zero = {0.f, 0.f, 0.f, 0.f};
        #pragma unroll
        for (int rf = 0; rf < 2; ++rf)
            #pragma unroll
            for (int cf = 0; cf < 4; ++cf)
                acc[rf][cf] = zero;

        #pragma unroll
        for (int ks = 0; ks < 8; ++ks) {
            const int kb = ks * 64 + ((lane >> 4) << 4);
            s16x8 bfr[4];
            #pragma unroll
            for (int cf = 0; cf < 4; ++cf) {
                const int row = cf * 16 + (lane & 15);
                bfr[cf] = *(const s16x8*)((const char*)Bs + row * 512 + (kb ^ ((row & 7) << 4)));
            }
            #pragma unroll
            for (int rf = 0; rf < 2; ++rf)
                #pragma unroll
                for (int cf = 0; cf < 4; ++cf)
                    acc[rf][cf] = __builtin_amdgcn_mfma_f32_16x16x32_bf16(
                        areg[ks][rf], bfr[cf], acc[rf][cf], 0, 0, 0);
        }

        #pragma unroll
        for (int cf = 0; cf < 4; ++cf) {
            const int n = nt * 64 + cf * 16 + (lane & 15);
            const float bv = BIAS ? bias[n] : 0.f;
            #pragma unroll
            for (int rf = 0; rf < 2; ++rf) {
                #pragma unroll
                for (int r = 0; r < 4; ++r) {
                    const int m = m0 + w * 32 + rf * 16 + ((lane >> 4) << 2) + r;
                    if (m < M) {
                        const float v = acc[rf][cf][r] + bv;
                        const size_t co = (size_t)z * bCstr + (size_t)m * sC + n;
                        if constexpr (OUTBF16) ((unsigned short*)Cp)[co] = f2bf(v);
                        else                   ((float*)Cp)[co] = v;
                    }
                }
            }
        }
        __syncthreads();
    }
}

// ---------------------------------------------------------------------------
// Build MS [128][256] bf16 + cbias[128]:
//   rows  0..63 : M1[a] = qa_s @ W_k  (cbias = b_k . qa_s[a])   [stage-1]
//   rows 64..127: M2[a] = ka_s @ W_q  (cbias = b_q . ka_s[a])   [stage-2]
// qa_s/ka_s include the 1/16 softmax scale.
// ---------------------------------------------------------------------------
__global__ __launch_bounds__(256) void build_M2(
    const float* __restrict__ W_qkv, const float* __restrict__ b_qkv,
    const float* __restrict__ qa_out,
    unsigned short* __restrict__ MS, float* __restrict__ cbias)
{
    const int i = blockIdx.x;  // 0..127
    const int t = threadIdx.x;
    __shared__ float qs[256];
    const int a = i & 63;
    const bool isS1 = (i < 64);
    qs[t] = qa_out[(size_t)a * 512 + (isS1 ? t : 256 + t)] * 0.0625f;
    __syncthreads();
    const float* W  = W_qkv + (isS1 ? 256 * 256 : 0);   // W_k : W_q
    const float* bb = b_qkv + (isS1 ? 256 : 0);
    float acc = 0.f, cb = 0.f;
    for (int dout = 0; dout < 256; ++dout) {
        const float q = qs[dout];
        acc += q * W[(size_t)dout * 256 + t];
        cb  += q * bb[dout];
    }
    MS[i * 256 + t] = f2bf(acc);
    if (t == 0) cbias[i] = cb;
}

// ---------------------------------------------------------------------------
// Streaming scores: per 64-token block computes S1T[n][a], S2[n][a] (f32)
// and stage-1 softmax partials.  A = x tile (LDS bf16, swizzled); B = MS
// (128 rows, L2-resident bf16).  No v computed (folded into fc chain).
// ---------------------------------------------------------------------------
__global__ __launch_bounds__(256) void xproj2(
    const float* __restrict__ x,
    const unsigned short* __restrict__ MS,
    const float* __restrict__ cbias,
    float* __restrict__ S1T,
    float* __restrict__ S2,
    float* __restrict__ mpart, float* __restrict__ lpart)
{
    __shared__ alignas(16) unsigned short As[64 * 256];   // 32KB
    const int tid = threadIdx.x, lane = tid & 63, w = tid >> 6;
    const int lr = lane & 15, lq = lane >> 4;
    const long m0 = (long)blockIdx.x * 64;

    // stage x tile (64 x 256 f32 -> bf16 LDS, XOR swizzled)
    {
        const int k0 = (tid & 31) * 8;
        #pragma unroll
        for (int j = 0; j < 8; ++j) {
            const int row = (tid >> 5) + j * 8;
            const float* s = x + (m0 + row) * 256 + k0;
            f32x4 f0 = *(const f32x4*)s;
            f32x4 f1 = *(const f32x4*)(s + 4);
            *(s16x8*)((char*)As + row * 512 + ((k0 * 2) ^ ((row & 7) << 4))) = pack8(f0, f1);
        }
    }
    __syncthreads();

    f32x4 acc[4][2];
    const f32x4 zero = {0.f, 0.f, 0.f, 0.f};
    #pragma unroll
    for (int rf = 0; rf < 4; ++rf)
        #pragma unroll
        for (int j = 0; j < 2; ++j)
            acc[rf][j] = zero;

    #pragma unroll
    for (int ks = 0; ks < 8; ++ks) {
        const int kb = ks * 64 + lq * 16;
        s16x8 areg[4];
        #pragma unroll
        for (int rf = 0; rf < 4; ++rf) {
            const int row = rf * 16 + lr;
            areg[rf] = *(const s16x8*)((const char*)As + row * 512 + (kb ^ ((row & 7) << 4)));
        }
        s16x8 bfr[2];
        #pragma unroll
        for (int j = 0; j < 2; ++j) {
            const int msrow = j * 64 + w * 16 + lr;
            bfr[j] = *(const s16x8*)((const char*)MS + (size_t)msrow * 512 + kb);
        }
        #pragma unroll
        for (int rf = 0; rf < 4; ++rf)
            #pragma unroll
            for (int j = 0; j < 2; ++j)
                acc[rf][j] = __builtin_amdgcn_mfma_f32_16x16x32_bf16(
                    areg[rf], bfr[j], acc[rf][j], 0, 0, 0);
    }

    // epilogue: j=0 -> S1T + partial stats, j=1 -> S2
    #pragma unroll
    for (int j = 0; j < 2; ++j) {
        const int a = w * 16 + lr;
        const float bv = cbias[j * 64 + a];
        float* dst = j ? S2 : S1T;
        float mx = -1e30f;
        #pragma unroll
        for (int rf = 0; rf < 4; ++rf)
            #pragma unroll
            for (int r = 0; r < 4; ++r) {
                const float v = acc[rf][j][r] + bv;
                dst[(m0 + rf * 16 + lq * 4 + r) * 64 + a] = v;
                mx = fmaxf(mx, v);
            }
        if (j == 0) {
            mx = fmaxf(mx, __shfl_xor(mx, 16));
            mx = fmaxf(mx, __shfl_xor(mx, 32));
            float sm = 0.f;
            #pragma unroll
            for (int rf = 0; rf < 4; ++rf)
                #pragma unroll
                for (int r = 0; r < 4; ++r)
                    sm += __expf(acc[rf][j][r] + bv - mx);
            sm += __shfl_xor(sm, 16);
            sm += __shfl_xor(sm, 32);
            if (lq == 0) {
                mpart[(size_t)blockIdx.x * 64 + a] = mx;
                lpart[(size_t)blockIdx.x * 64 + a] = sm;
            }
        }
    }
}

// ---------------------------------------------------------------------------
// Combine stage-1 partials (128 chunks of 64 tokens per batch).
// ---------------------------------------------------------------------------
__global__ __launch_bounds__(256) void s1_combine(const float* __restrict__ mpart,
                                                  const float* __restrict__ lpart,
                                                  float* __restrict__ m1,
                                                  float* __restrict__ l1inv)
{
    const int b = blockIdx.x;
    const int a = threadIdx.x & 63, s = threadIdx.x >> 6;
    float M = -1e30f;
    for (int c = s; c < 128; c += 4)
        M = fmaxf(M, mpart[((size_t)b * 128 + c) * 64 + a]);
    float L = 0.f;
    for (int c = s; c < 128; c += 4) {
        const size_t idx = ((size_t)b * 128 + c) * 64 + a;
        L += lpart[idx] * __expf(mpart[idx] - M);
    }
    __shared__ float ms[256], ls[256];
    ms[threadIdx.x] = M; ls[threadIdx.x] = L;
    __syncthreads();
    if (threadIdx.x < 64) {
        const int aa = threadIdx.x;
        float Mm = ms[aa];
        #pragma unroll
        for (int ss = 1; ss < 4; ++ss) Mm = fmaxf(Mm, ms[ss * 64 + aa]);
        float Ll = 0.f;
        #pragma unroll
        for (int ss = 0; ss < 4; ++ss) Ll += ls[ss * 64 + aa] * __expf(ms[ss * 64 + aa] - Mm);
        m1[b * 64 + aa] = Mm;
        l1inv[b * 64 + aa] = 1.0f / Ll;
    }
}

// ---------------------------------------------------------------------------
// y = attn1 @ x via MFMA: y_part[b][c][64 a][256 d] = P(chunk) @ X(chunk)^T.
// P[a][n] = exp(S1-m1)*l1inv (bf16, LDS transpose of S1T[n][a]);
// XT[d][n] = bf16 LDS transpose of x rows (f32, row-major reads).
// Grid: (c=32 n-chunks of 256, dh=2 d-halves, b=8); K-tiles of 128.
// ---------------------------------------------------------------------------
__global__ __launch_bounds__(256) void pv_mfma2(
    const float* __restrict__ S1T,
    const float* __restrict__ x,
    const float* __restrict__ m1,
    const float* __restrict__ l1inv,
    float* __restrict__ y_part)
{
    __shared__ alignas(16) unsigned short P_lds[64 * 128];   // [a][n] 16KB
    __shared__ alignas(16) unsigned short XT[128 * 136];     // [d][136n] ~35KB (pad row)
    const int tid = threadIdx.x, lane = tid & 63, w = tid >> 6;
    const int lr = lane & 15, lq = lane >> 4;
    const int c = blockIdx.x, dh = blockIdx.y, b = blockIdx.z;

    const int a4 = (tid & 15) * 4;
    const f32x4 m4 = *(const f32x4*)&m1[b * 64 + a4];
    const f32x4 l4 = *(const f32x4*)&l1inv[b * 64 + a4];

    f32x4 acc[4][2];
    const f32x4 zero = {0.f, 0.f, 0.f, 0.f};
    #pragma unroll
    for (int rf = 0; rf < 4; ++rf)
        #pragma unroll
        for (int cf = 0; cf < 2; ++cf)
            acc[rf][cf] = zero;

    for (int kt = 0; kt < 2; ++kt) {
        const size_t ng0 = (size_t)b * 8192 + c * 256 + kt * 128;
        // ---- P stage: S1T[n][a] f32 -> exp -> bf16 P_lds[a][n] ----
        #pragma unroll
        for (int pass = 0; pass < 4; ++pass) {
            const int np = 2 * (tid >> 4) + pass * 32;
            const float* s = S1T + (ng0 + np) * 64 + a4;
            f32x4 s0 = *(const f32x4*)s;
            f32x4 s1 = *(const f32x4*)(s + 64);
            #pragma unroll
            for (int j = 0; j < 4; ++j) {
                const int a = a4 + j;
                const float p0 = __expf(s0[j] - m4[j]) * l4[j];
                const float p1 = __expf(s1[j] - m4[j]) * l4[j];
                const unsigned int pk = (unsigned int)f2bf(p0) | ((unsigned int)f2bf(p1) << 16);
                *(unsigned int*)((char*)P_lds + a * 256 + ((np * 2) ^ (((a >> 1) & 7) << 4))) = pk;
            }
        }
        // ---- XT stage: x[n][d] f32 -> bf16 XT[d][n], pair-packed b32 ----
        {
            const int nh = tid >> 2;          // n-pair index 0..63
            const int dq = tid & 3;           // d-quad 0..3
            const float* xbase = x + (ng0 + 2 * nh) * 256 + dh * 128;
            #pragma unroll
            for (int pass = 0; pass < 8; ++pass) {
                const int dl0 = pass * 16 + dq * 4;
                f32x4 xa = *(const f32x4*)(xbase + dl0);
                f32x4 xb = *(const f32x4*)(xbase + 256 + dl0);
                #pragma unroll
                for (int jj = 0; jj < 4; ++jj) {
                    const unsigned int pk = (unsigned int)f2bf(xa[jj]) | ((unsigned int)f2bf(xb[jj]) << 16);
                    *(unsigned int*)((char*)XT + (dl0 + jj) * 272 + nh * 4) = pk;
                }
            }
        }
        __syncthreads();
        #pragma unroll
        for (int ks = 0; ks < 4; ++ks) {
            const int kbn = ks * 64 + lq * 16;   // byte offset along n
            s16x8 af[4], bfv[2];
            #pragma unroll
            for (int rf = 0; rf < 4; ++rf) {
                const int row = rf * 16 + lr;
                af[rf] = *(const s16x8*)((const char*)P_lds + row * 256 + (kbn ^ (((row >> 1) & 7) << 4)));
            }
            #pragma unroll
            for (int cf = 0; cf < 2; ++cf) {
                const int dl = w * 32 + cf * 16 + lr;
                bfv[cf] = *(const s16x8*)((const char*)XT + dl * 272 + kbn);
            }
            #pragma unroll
            for (int rf = 0; rf < 4; ++rf)
                #pragma unroll
                for (int cf = 0; cf < 2; ++cf)
                    acc[rf][cf] = __builtin_amdgcn_mfma_f32_16x16x32_bf16(
                        af[rf], bfv[cf], acc[rf][cf], 0, 0, 0);
        }
        __syncthreads();
    }
    #pragma unroll
    for (int rf = 0; rf < 4; ++rf)
        #pragma unroll
        for (int cf = 0; cf < 2; ++cf)
            #pragma unroll
            for (int r = 0; r < 4; ++r) {
                const int a = rf * 16 + lq * 4 + r;
                const int d = dh * 128 + w * 32 + cf * 16 + lr;
                y_part[(((size_t)b * 32 + c) * 64 + a) * 256 + d] = acc[rf][cf][r];
            }
}

__global__ void v1_reduce(const float* __restrict__ y_part,
                          float* __restrict__ y_raw)
{
    const int a = blockIdx.x, b = blockIdx.y, t = threadIdx.x;  // 64 thr
    f32x4 s = {0.f, 0.f, 0.f, 0.f};
    for (int c = 0; c < 32; ++c)
        s += *(const f32x4*)&y_part[(((size_t)b * 32 + c) * 64 + a) * 256 + t * 4];
    *(f32x4*)&y_raw[((size_t)b * 64 + a) * 256 + t * 4] = s;
}

// ---------------------------------------------------------------------------
// Stage-2 fused: softmax(64) + PV against u (bf16 LDS) + residual + RMSNorm.
// ---------------------------------------------------------------------------
__global__ __launch_bounds__(256) void stage2_final(const float* __restrict__ S2,
                                                    const unsigned short* __restrict__ u,
                                                    const float* __restrict__ x,
                                                    const float* __restrict__ nscale,
                                                    float* __restrict__ out)
{
    __shared__ unsigned short u_s[64 * 256];   // 32KB bf16
    __shared__ float p_s[4][64][4];
    const int tid = threadIdx.x;
    const int b = blockIdx.x >> 7;
    const unsigned short* ub = u + (size_t)b * 64 * 256;
    #pragma unroll
    for (int i = 0; i < 8; ++i) {
        const int off = i * 2048 + tid * 8;
        *(s16x8*)&u_s[off] = *(const s16x8*)&ub[off];
    }
    __syncthreads();
    const int w = tid >> 6, lane = tid & 63;
    const f32x4 sc4 = *(const f32x4*)&nscale[lane * 4];
    const int tok0 = blockIdx.x * 64 + w * 16;
    const f32x4 zero = {0.f, 0.f, 0.f, 0.f};

    for (int q4 = 0; q4 < 4; ++q4) {
        const int n0 = tok0 + q4 * 4;
        #pragma unroll
        for (int g = 0; g < 4; ++g) {
            const int n = n0 + g;
            float s = S2[(size_t)n * 64 + lane];
            float mx = s;
            #pragma unroll
            for (int off = 32; off; off >>= 1) mx = fmaxf(mx, __shfl_xor(mx, off));
            float p = __expf(s - mx);
            float sm = p;
            #pragma unroll
            for (int off = 32; off; off >>= 1) sm += __shfl_xor(sm, off);
            p_s[w][lane][g] = p / sm;
        }
        f32x4 a0 = zero, a1 = zero, a2 = zero, a3 = zero;
        const unsigned short* ur = &u_s[lane * 4];
        #pragma unroll 8
        for (int a = 0; a < 64; ++a) {
            const s16x4 up = *(const s16x4*)(ur + a * 256);
            f32x4 uv;
            uv[0] = bf2f((unsigned short)up[0]); uv[1] = bf2f((unsigned short)up[1]);
            uv[2] = bf2f((unsigned short)up[2]); uv[3] = bf2f((unsigned short)up[3]);
            const f32x4 pq = *(const f32x4*)&p_s[w][a][0];
            a0 += uv * pq[0];
            a1 += uv * pq[1];
            a2 += uv * pq[2];
            a3 += uv * pq[3];
        }
        #pragma unroll
        for (int g = 0; g < 4; ++g) {
            const int n = n0 + g;
            const f32x4 xr = *(const f32x4*)&x[(size_t)n * 256 + lane * 4];
            const f32x4 vg = (g == 0) ? a0 : (g == 1) ? a1 : (g == 2) ? a2 : a3;
            f32x4 y = vg + xr;
            float ss = y[0] * y[0] + y[1] * y[1] + y[2] * y[2] + y[3] * y[3];
            #pragma unroll
            for (int off = 32; off; off >>= 1) ss += __shfl_xor(ss, off);
            const float inv = 1.f / (sqrtf(ss) * 0.0625f + 1e-8f);
            f32x4 o = sc4 * y * inv;
            *(f32x4*)&out[(size_t)n * 256 + lane * 4] = o;
        }
    }
}

// ---------------------------------------------------------------------------
extern "C" void kernel_launch(void* const* d_in, const int* in_sizes, int n_in,
                              void* d_out, int out_size, void* d_ws, size_t ws_size,
                              hipStream_t stream)
{
    const float* agent   = (const float*)d_in[0];
    const float* x       = (const float*)d_in[1];
    const float* W_qkv   = (const float*)d_in[2];
    const float* b_qkv   = (const float*)d_in[3];
    const float* W_agent = (const float*)d_in[4];
    const float* b_agent = (const float*)d_in[5];
    const float* W_fc1   = (const float*)d_in[6];
    const float* b_fc1   = (const float*)d_in[7];
    const float* W_fc2   = (const float*)d_in[8];
    const float* b_fc2   = (const float*)d_in[9];
    const float* nscale  = (const float*)d_in[10];
    float* out = (float*)d_out;

    char* wsp = (char*)d_ws;
    size_t off = 0;
    auto alloc = [&](size_t n) { void* p = wsp + off; off += (n + 255) & ~(size_t)255; return p; };

    float*  qa_out = (float*)alloc(64UL * 512 * 4);
    unsigned short* MS = (unsigned short*)alloc(128UL * 256 * 2);
    float*  cbias  = (float*)alloc(128UL * 4);
    float*  S1T    = (float*)alloc(65536UL * 64 * 4);   // [n][a]
    float*  S2     = (float*)alloc(65536UL * 64 * 4);   // [n][a]
    float*  mpart  = (float*)alloc(1024UL * 64 * 4);
    float*  lpart  = (float*)alloc(1024UL * 64 * 4);
    float*  m1     = (float*)alloc(512UL * 4);
    float*  l1inv  = (float*)alloc(512UL * 4);
    float*  y_part = (float*)alloc(8UL * 32 * 64 * 256 * 4);
    float*  y_raw  = (float*)alloc(512UL * 256 * 4);
    float*  t0     = (float*)alloc(512UL * 256 * 4);
    float*  t1     = (float*)alloc(512UL * 256 * 4);
    unsigned short* uu = (unsigned short*)alloc(512UL * 256 * 2);

    // 1. agent projection: [64][512] f32
    gemm_k256<true, true, false, true><<<dim3(1, 1, 1), 256, 0, stream>>>(
        agent, 256, 0, W_agent, 256, b_agent, qa_out, 512, 0, 64, 512);
    // 2. score matrices M1|M2 + bias consts
    build_M2<<<128, 256, 0, stream>>>(W_qkv, b_qkv, qa_out, MS, cbias);
    // 3. streaming scores S1T, S2 + stage-1 softmax partials (no v!)
    xproj2<<<1024, 256, 0, stream>>>(x, MS, cbias, S1T, S2, mpart, lpart);
    // 4. combine stage-1 stats
    s1_combine<<<8, 256, 0, stream>>>(mpart, lpart, m1, l1inv);
    // 5. y = attn1 @ x via MFMA (partials over 32 n-chunks)
    pv_mfma2<<<dim3(32, 2, 8), 256, 0, stream>>>(S1T, x, m1, l1inv, y_part);
    // 6. reduce partials -> y_raw
    v1_reduce<<<dim3(64, 8), 64, 0, stream>>>(y_part, y_raw);
    // 7. folded chain: u = ((y@Wv^T+bv)@W1^T+b1)@W2^T+b2  (softmax rows sum to 1)
    gemm_k256<true, true, false, true><<<dim3(4, 1, 1), 256, 0, stream>>>(
        y_raw, 256, 0, W_qkv + 512 * 256, 256, b_qkv + 512, t0, 256, 0, 512, 256);
    gemm_k256<true, true, false, true><<<dim3(4, 1, 1), 256, 0, stream>>>(
        t0, 256, 0, W_fc1, 256, b_fc1, t1, 256, 0, 512, 256);
    gemm_k256<true, true, true, true><<<dim3(4, 1, 1), 256, 0, stream>>>(
        t1, 256, 0, W_fc2, 256, b_fc2, uu, 256, 0, 512, 256);
    // 8. softmax(64) + PV(u) + residual + rmsnorm
    stage2_final<<<1024, 256, 0, stream>>>(S2, uu, x, nscale, out);
}

// Round 5
// 153.739 us; speedup vs baseline: 2.8370x; 1.5614x over previous
//
#include <hip/hip_runtime.h>
#include <hip/hip_bf16.h>

typedef __attribute__((ext_vector_type(4))) float f32x4;
typedef __attribute__((ext_vector_type(8))) short s16x8;
typedef __attribute__((ext_vector_type(4))) short s16x4;

__device__ __forceinline__ unsigned short f2bf(float f) {
    unsigned int u; __builtin_memcpy(&u, &f, 4);
    u += 0x7fffu + ((u >> 16) & 1u);
    return (unsigned short)(u >> 16);
}
__device__ __forceinline__ float bf2f(unsigned short h) {
    unsigned int u = ((unsigned int)h) << 16;
    float f; __builtin_memcpy(&f, &u, 4);
    return f;
}
__device__ __forceinline__ s16x8 pack8(f32x4 a, f32x4 b) {
    s16x8 r;
    r[0] = (short)f2bf(a[0]); r[1] = (short)f2bf(a[1]);
    r[2] = (short)f2bf(a[2]); r[3] = (short)f2bf(a[3]);
    r[4] = (short)f2bf(b[0]); r[5] = (short)f2bf(b[1]);
    r[6] = (short)f2bf(b[2]); r[7] = (short)f2bf(b[3]);
    return r;
}

// ---------------------------------------------------------------------------
// Generic C = A @ B^T (+bias) GEMM, K=256 — small matmuls (agent proj, chain).
// Each block handles one 64-col tile (nt = blockIdx.y) of 128 rows.
// ---------------------------------------------------------------------------
template<bool AF32, bool BF32, bool OUTBF16, bool BIAS>
__global__ __launch_bounds__(256) void gemm_k256(
    const void* __restrict__ Ap, long sA, long bAstr,
    const void* __restrict__ Bp, long sB,
    const float* __restrict__ bias,
    void* __restrict__ Cp, long sC, long bCstr,
    int M, int N)
{
    __shared__ alignas(16) unsigned short As[128 * 256];
    __shared__ alignas(16) unsigned short Bs[64 * 256];
    const int tid = threadIdx.x;
    const int lane = tid & 63;
    const int w = tid >> 6;
    const int m0 = blockIdx.x * 128;
    const int nt = blockIdx.y;
    const int z = blockIdx.z;

    {
        const int kk = (tid & 31) * 8;
        #pragma unroll
        for (int j = 0; j < 16; ++j) {
            const int row = (tid >> 5) + j * 8;
            int rowg = m0 + row; if (rowg > M - 1) rowg = M - 1;
            s16x8 v;
            if constexpr (AF32) {
                const float* s = (const float*)Ap + (size_t)z * bAstr + (size_t)rowg * sA + kk;
                f32x4 f0 = *(const f32x4*)s;
                f32x4 f1 = *(const f32x4*)(s + 4);
                v = pack8(f0, f1);
            } else {
                const unsigned short* s = (const unsigned short*)Ap + (size_t)z * bAstr + (size_t)rowg * sA + kk;
                v = *(const s16x8*)s;
            }
            *(s16x8*)((char*)As + row * 512 + ((kk * 2) ^ ((row & 7) << 4))) = v;
        }
        // stage B tile for this block's col-tile
        #pragma unroll
        for (int j = 0; j < 8; ++j) {
            const int row = (tid >> 5) + j * 8;
            const int rowg = nt * 64 + row;
            s16x8 v;
            if constexpr (BF32) {
                const float* s = (const float*)Bp + (size_t)rowg * sB + kk;
                f32x4 f0 = *(const f32x4*)s;
                f32x4 f1 = *(const f32x4*)(s + 4);
                v = pack8(f0, f1);
            } else {
                const unsigned short* s = (const unsigned short*)Bp + (size_t)rowg * sB + kk;
                v = *(const s16x8*)s;
            }
            *(s16x8*)((char*)Bs + row * 512 + ((kk * 2) ^ ((row & 7) << 4))) = v;
        }
    }
    __syncthreads();

    f32x4 acc[2][4];
    const f32x4 zero = {0.f, 0.f, 0.f, 0.f};
    #pragma unroll
    for (int rf = 0; rf < 2; ++rf)
        #pragma unroll
        for (int cf = 0; cf < 4; ++cf)
            acc[rf][cf] = zero;

    #pragma unroll
    for (int ks = 0; ks < 8; ++ks) {
        const int kb = ks * 64 + ((lane >> 4) << 4);
        s16x8 areg[2], bfr[4];
        #pragma unroll
        for (int rf = 0; rf < 2; ++rf) {
            const int row = w * 32 + rf * 16 + (lane & 15);
            areg[rf] = *(const s16x8*)((const char*)As + row * 512 + (kb ^ ((row & 7) << 4)));
        }
        #pragma unroll
        for (int cf = 0; cf < 4; ++cf) {
            const int row = cf * 16 + (lane & 15);
            bfr[cf] = *(const s16x8*)((const char*)Bs + row * 512 + (kb ^ ((row & 7) << 4)));
        }
        #pragma unroll
        for (int rf = 0; rf < 2; ++rf)
            #pragma unroll
            for (int cf = 0; cf < 4; ++cf)
                acc[rf][cf] = __builtin_amdgcn_mfma_f32_16x16x32_bf16(
                    areg[rf], bfr[cf], acc[rf][cf], 0, 0, 0);
    }

    #pragma unroll
    for (int cf = 0; cf < 4; ++cf) {
        const int n = nt * 64 + cf * 16 + (lane & 15);
        const float bv = BIAS ? bias[n] : 0.f;
        #pragma unroll
        for (int rf = 0; rf < 2; ++rf) {
            #pragma unroll
            for (int r = 0; r < 4; ++r) {
                const int m = m0 + w * 32 + rf * 16 + ((lane >> 4) << 2) + r;
                if (m < M) {
                    const float v = acc[rf][cf][r] + bv;
                    const size_t co = (size_t)z * bCstr + (size_t)m * sC + n;
                    if constexpr (OUTBF16) ((unsigned short*)Cp)[co] = f2bf(v);
                    else                   ((float*)Cp)[co] = v;
                }
            }
        }
    }
}

// ---------------------------------------------------------------------------
// Build MS [128][256] bf16 + cbias[128]:
//   rows  0..63 : M1[a] = qa_s @ W_k  (cbias = b_k . qa_s[a])   [stage-1]
//   rows 64..127: M2[a] = ka_s @ W_q  (cbias = b_q . ka_s[a])   [stage-2]
// ---------------------------------------------------------------------------
__global__ __launch_bounds__(256) void build_M2(
    const float* __restrict__ W_qkv, const float* __restrict__ b_qkv,
    const float* __restrict__ qa_out,
    unsigned short* __restrict__ MS, float* __restrict__ cbias)
{
    const int i = blockIdx.x;  // 0..127
    const int t = threadIdx.x;
    __shared__ float qs[256];
    const int a = i & 63;
    const bool isS1 = (i < 64);
    qs[t] = qa_out[(size_t)a * 512 + (isS1 ? t : 256 + t)] * 0.0625f;
    __syncthreads();
    const float* W  = W_qkv + (isS1 ? 256 * 256 : 0);   // W_k : W_q
    const float* bb = b_qkv + (isS1 ? 256 : 0);
    float acc = 0.f, cb = 0.f;
    for (int dout = 0; dout < 256; ++dout) {
        const float q = qs[dout];
        acc += q * W[(size_t)dout * 256 + t];
        cb  += q * bb[dout];
    }
    MS[i * 256 + t] = f2bf(acc);
    if (t == 0) cbias[i] = cb;
}

// ---------------------------------------------------------------------------
// Streaming scores: per 64-token block computes S1T[n][a], S2[n][a] (f32)
// and stage-1 softmax partials.
// ---------------------------------------------------------------------------
__global__ __launch_bounds__(256) void xproj2(
    const float* __restrict__ x,
    const unsigned short* __restrict__ MS,
    const float* __restrict__ cbias,
    float* __restrict__ S1T,
    float* __restrict__ S2,
    float* __restrict__ mpart, float* __restrict__ lpart)
{
    __shared__ alignas(16) unsigned short As[64 * 256];   // 32KB
    const int tid = threadIdx.x, lane = tid & 63, w = tid >> 6;
    const int lr = lane & 15, lq = lane >> 4;
    const long m0 = (long)blockIdx.x * 64;

    {
        const int k0 = (tid & 31) * 8;
        #pragma unroll
        for (int j = 0; j < 8; ++j) {
            const int row = (tid >> 5) + j * 8;
            const float* s = x + (m0 + row) * 256 + k0;
            f32x4 f0 = *(const f32x4*)s;
            f32x4 f1 = *(const f32x4*)(s + 4);
            *(s16x8*)((char*)As + row * 512 + ((k0 * 2) ^ ((row & 7) << 4))) = pack8(f0, f1);
        }
    }
    __syncthreads();

    f32x4 acc[4][2];
    const f32x4 zero = {0.f, 0.f, 0.f, 0.f};
    #pragma unroll
    for (int rf = 0; rf < 4; ++rf)
        #pragma unroll
        for (int j = 0; j < 2; ++j)
            acc[rf][j] = zero;

    #pragma unroll
    for (int ks = 0; ks < 8; ++ks) {
        const int kb = ks * 64 + lq * 16;
        s16x8 areg[4];
        #pragma unroll
        for (int rf = 0; rf < 4; ++rf) {
            const int row = rf * 16 + lr;
            areg[rf] = *(const s16x8*)((const char*)As + row * 512 + (kb ^ ((row & 7) << 4)));
        }
        s16x8 bfr[2];
        #pragma unroll
        for (int j = 0; j < 2; ++j) {
            const int msrow = j * 64 + w * 16 + lr;
            bfr[j] = *(const s16x8*)((const char*)MS + (size_t)msrow * 512 + kb);
        }
        #pragma unroll
        for (int rf = 0; rf < 4; ++rf)
            #pragma unroll
            for (int j = 0; j < 2; ++j)
                acc[rf][j] = __builtin_amdgcn_mfma_f32_16x16x32_bf16(
                    areg[rf], bfr[j], acc[rf][j], 0, 0, 0);
    }

    #pragma unroll
    for (int j = 0; j < 2; ++j) {
        const int a = w * 16 + lr;
        const float bv = cbias[j * 64 + a];
        float* dst = j ? S2 : S1T;
        float mx = -1e30f;
        #pragma unroll
        for (int rf = 0; rf < 4; ++rf)
            #pragma unroll
            for (int r = 0; r < 4; ++r) {
                const float v = acc[rf][j][r] + bv;
                dst[(m0 + rf * 16 + lq * 4 + r) * 64 + a] = v;
                mx = fmaxf(mx, v);
            }
        if (j == 0) {
            mx = fmaxf(mx, __shfl_xor(mx, 16));
            mx = fmaxf(mx, __shfl_xor(mx, 32));
            float sm = 0.f;
            #pragma unroll
            for (int rf = 0; rf < 4; ++rf)
                #pragma unroll
                for (int r = 0; r < 4; ++r)
                    sm += __expf(acc[rf][j][r] + bv - mx);
            sm += __shfl_xor(sm, 16);
            sm += __shfl_xor(sm, 32);
            if (lq == 0) {
                mpart[(size_t)blockIdx.x * 64 + a] = mx;
                lpart[(size_t)blockIdx.x * 64 + a] = sm;
            }
        }
    }
}

// ---------------------------------------------------------------------------
// Combine stage-1 partials (128 chunks of 64 tokens per batch).
// ---------------------------------------------------------------------------
__global__ __launch_bounds__(256) void s1_combine(const float* __restrict__ mpart,
                                                  const float* __restrict__ lpart,
                                                  float* __restrict__ m1,
                                                  float* __restrict__ l1inv)
{
    const int b = blockIdx.x;
    const int a = threadIdx.x & 63, s = threadIdx.x >> 6;
    float M = -1e30f;
    for (int c = s; c < 128; c += 4)
        M = fmaxf(M, mpart[((size_t)b * 128 + c) * 64 + a]);
    float L = 0.f;
    for (int c = s; c < 128; c += 4) {
        const size_t idx = ((size_t)b * 128 + c) * 64 + a;
        L += lpart[idx] * __expf(mpart[idx] - M);
    }
    __shared__ float ms[256], ls[256];
    ms[threadIdx.x] = M; ls[threadIdx.x] = L;
    __syncthreads();
    if (threadIdx.x < 64) {
        const int aa = threadIdx.x;
        float Mm = ms[aa];
        #pragma unroll
        for (int ss = 1; ss < 4; ++ss) Mm = fmaxf(Mm, ms[ss * 64 + aa]);
        float Ll = 0.f;
        #pragma unroll
        for (int ss = 0; ss < 4; ++ss) Ll += ls[ss * 64 + aa] * __expf(ms[ss * 64 + aa] - Mm);
        m1[b * 64 + aa] = Mm;
        l1inv[b * 64 + aa] = 1.0f / Ll;
    }
}

// ---------------------------------------------------------------------------
// y = attn1 @ x via MFMA (partials over 32 n-chunks of 256).
// ---------------------------------------------------------------------------
__global__ __launch_bounds__(256) void pv_mfma2(
    const float* __restrict__ S1T,
    const float* __restrict__ x,
    const float* __restrict__ m1,
    const float* __restrict__ l1inv,
    float* __restrict__ y_part)
{
    __shared__ alignas(16) unsigned short P_lds[64 * 128];   // [a][n] 16KB
    __shared__ alignas(16) unsigned short XT[128 * 136];     // [d][136n] (pad row)
    const int tid = threadIdx.x, lane = tid & 63, w = tid >> 6;
    const int lr = lane & 15, lq = lane >> 4;
    const int c = blockIdx.x, dh = blockIdx.y, b = blockIdx.z;

    const int a4 = (tid & 15) * 4;
    const f32x4 m4 = *(const f32x4*)&m1[b * 64 + a4];
    const f32x4 l4 = *(const f32x4*)&l1inv[b * 64 + a4];

    f32x4 acc[4][2];
    const f32x4 zero = {0.f, 0.f, 0.f, 0.f};
    #pragma unroll
    for (int rf = 0; rf < 4; ++rf)
        #pragma unroll
        for (int cf = 0; cf < 2; ++cf)
            acc[rf][cf] = zero;

    for (int kt = 0; kt < 2; ++kt) {
        const size_t ng0 = (size_t)b * 8192 + c * 256 + kt * 128;
        #pragma unroll
        for (int pass = 0; pass < 4; ++pass) {
            const int np = 2 * (tid >> 4) + pass * 32;
            const float* s = S1T + (ng0 + np) * 64 + a4;
            f32x4 s0 = *(const f32x4*)s;
            f32x4 s1 = *(const f32x4*)(s + 64);
            #pragma unroll
            for (int j = 0; j < 4; ++j) {
                const int a = a4 + j;
                const float p0 = __expf(s0[j] - m4[j]) * l4[j];
                const float p1 = __expf(s1[j] - m4[j]) * l4[j];
                const unsigned int pk = (unsigned int)f2bf(p0) | ((unsigned int)f2bf(p1) << 16);
                *(unsigned int*)((char*)P_lds + a * 256 + ((np * 2) ^ (((a >> 1) & 7) << 4))) = pk;
            }
        }
        {
            const int nh = tid >> 2;
            const int dq = tid & 3;
            const float* xbase = x + (ng0 + 2 * nh) * 256 + dh * 128;
            #pragma unroll
            for (int pass = 0; pass < 8; ++pass) {
                const int dl0 = pass * 16 + dq * 4;
                f32x4 xa = *(const f32x4*)(xbase + dl0);
                f32x4 xb = *(const f32x4*)(xbase + 256 + dl0);
                #pragma unroll
                for (int jj = 0; jj < 4; ++jj) {
                    const unsigned int pk = (unsigned int)f2bf(xa[jj]) | ((unsigned int)f2bf(xb[jj]) << 16);
                    *(unsigned int*)((char*)XT + (dl0 + jj) * 272 + nh * 4) = pk;
                }
            }
        }
        __syncthreads();
        #pragma unroll
        for (int ks = 0; ks < 4; ++ks) {
            const int kbn = ks * 64 + lq * 16;
            s16x8 af[4], bfv[2];
            #pragma unroll
            for (int rf = 0; rf < 4; ++rf) {
                const int row = rf * 16 + lr;
                af[rf] = *(const s16x8*)((const char*)P_lds + row * 256 + (kbn ^ (((row >> 1) & 7) << 4)));
            }
            #pragma unroll
            for (int cf = 0; cf < 2; ++cf) {
                const int dl = w * 32 + cf * 16 + lr;
                bfv[cf] = *(const s16x8*)((const char*)XT + dl * 272 + kbn);
            }
            #pragma unroll
            for (int rf = 0; rf < 4; ++rf)
                #pragma unroll
                for (int cf = 0; cf < 2; ++cf)
                    acc[rf][cf] = __builtin_amdgcn_mfma_f32_16x16x32_bf16(
                        af[rf], bfv[cf], acc[rf][cf], 0, 0, 0);
        }
        __syncthreads();
    }
    #pragma unroll
    for (int rf = 0; rf < 4; ++rf)
        #pragma unroll
        for (int cf = 0; cf < 2; ++cf)
            #pragma unroll
            for (int r = 0; r < 4; ++r) {
                const int a = rf * 16 + lq * 4 + r;
                const int d = dh * 128 + w * 32 + cf * 16 + lr;
                y_part[(((size_t)b * 32 + c) * 64 + a) * 256 + d] = acc[rf][cf][r];
            }
}

__global__ void v1_reduce(const float* __restrict__ y_part,
                          float* __restrict__ y_raw)
{
    const int a = blockIdx.x, b = blockIdx.y, t = threadIdx.x;  // 64 thr
    f32x4 s = {0.f, 0.f, 0.f, 0.f};
    for (int c = 0; c < 32; ++c)
        s += *(const f32x4*)&y_part[(((size_t)b * 32 + c) * 64 + a) * 256 + t * 4];
    *(f32x4*)&y_raw[((size_t)b * 64 + a) * 256 + t * 4] = s;
}

// ---------------------------------------------------------------------------
// Stage-2 fused: softmax(64) + PV via MFMA (P bf16, uT bf16 LDS) + residual
// + RMSNorm.  Block = 64 tokens, wave w owns d-range [w*64, w*64+64).
// ---------------------------------------------------------------------------
__global__ __launch_bounds__(256) void stage2_final(const float* __restrict__ S2,
                                                    const float* __restrict__ uu,
                                                    const float* __restrict__ x,
                                                    const float* __restrict__ nscale,
                                                    float* __restrict__ out)
{
    __shared__ alignas(16) unsigned short uT[256 * 64];  // [d][a] pitch 128B, swz
    __shared__ alignas(16) unsigned short P[64 * 64];    // [nl][a] pitch 128B, swz
    __shared__ float ssq[4][64];
    const int tid = threadIdx.x, lane = tid & 63, w = tid >> 6;
    const int lr = lane & 15, lq = lane >> 4;
    const int b = blockIdx.x >> 7;
    const long n0 = (long)blockIdx.x * 64;

    // ---- stage uT[d][a] bf16 from uu[b][a][d] f32 (pair-packed transpose) ----
    {
        const int pr = tid >> 3;      // a-pair 0..31
        const int sub = tid & 7;
        const float* u0 = uu + ((size_t)b * 64 + 2 * pr) * 256;
        #pragma unroll
        for (int pass = 0; pass < 8; ++pass) {
            const int d0 = pass * 32 + sub * 4;
            f32x4 ua = *(const f32x4*)(u0 + d0);
            f32x4 ub = *(const f32x4*)(u0 + 256 + d0);
            #pragma unroll
            for (int jj = 0; jj < 4; ++jj) {
                const int d = d0 + jj;
                const unsigned int pk = (unsigned int)f2bf(ua[jj]) | ((unsigned int)f2bf(ub[jj]) << 16);
                *(unsigned int*)((char*)uT + d * 128 + ((pr * 4) ^ ((d & 7) << 4))) = pk;
            }
        }
    }
    // ---- softmax per token (16 per wave), write P bf16 [nl][a] ----
    for (int t = 0; t < 16; ++t) {
        const int nl = w * 16 + t;
        float s = S2[(n0 + nl) * 64 + lane];
        float mx = s;
        #pragma unroll
        for (int off = 32; off; off >>= 1) mx = fmaxf(mx, __shfl_xor(mx, off));
        float p = __expf(s - mx);
        float sm = p;
        #pragma unroll
        for (int off = 32; off; off >>= 1) sm += __shfl_xor(sm, off);
        p /= sm;
        *(unsigned short*)((char*)P + nl * 128 + ((lane * 2) ^ ((nl & 7) << 4))) = f2bf(p);
    }
    __syncthreads();

    // ---- PV MFMA: out[n][d] = P[n][a] @ uT[d][a], k = 64 agents ----
    f32x4 acc[4][4];
    const f32x4 zero = {0.f, 0.f, 0.f, 0.f};
    #pragma unroll
    for (int rf = 0; rf < 4; ++rf)
        #pragma unroll
        for (int cf = 0; cf < 4; ++cf)
            acc[rf][cf] = zero;
    #pragma unroll
    for (int ks = 0; ks < 2; ++ks) {
        const int kb = ks * 64 + lq * 16;
        s16x8 af[4], bfv[4];
        #pragma unroll
        for (int rf = 0; rf < 4; ++rf) {
            const int row = rf * 16 + lr;
            af[rf] = *(const s16x8*)((const char*)P + row * 128 + (kb ^ ((row & 7) << 4)));
        }
        #pragma unroll
        for (int cf = 0; cf < 4; ++cf) {
            const int dr = w * 64 + cf * 16 + lr;
            bfv[cf] = *(const s16x8*)((const char*)uT + dr * 128 + (kb ^ ((dr & 7) << 4)));
        }
        #pragma unroll
        for (int rf = 0; rf < 4; ++rf)
            #pragma unroll
            for (int cf = 0; cf < 4; ++cf)
                acc[rf][cf] = __builtin_amdgcn_mfma_f32_16x16x32_bf16(
                    af[rf], bfv[cf], acc[rf][cf], 0, 0, 0);
    }

    // ---- residual + rmsnorm ----
    float sc[4];
    #pragma unroll
    for (int cf = 0; cf < 4; ++cf) sc[cf] = nscale[w * 64 + cf * 16 + lr];

    #pragma unroll
    for (int rf = 0; rf < 4; ++rf)
        #pragma unroll
        for (int cf = 0; cf < 4; ++cf) {
            const int d = w * 64 + cf * 16 + lr;
            #pragma unroll
            for (int r = 0; r < 4; ++r) {
                const long n = n0 + rf * 16 + lq * 4 + r;
                acc[rf][cf][r] += x[n * 256 + d];
            }
        }
    #pragma unroll
    for (int rf = 0; rf < 4; ++rf)
        #pragma unroll
        for (int r = 0; r < 4; ++r) {
            float s = 0.f;
            #pragma unroll
            for (int cf = 0; cf < 4; ++cf) s += acc[rf][cf][r] * acc[rf][cf][r];
            s += __shfl_xor(s, 1); s += __shfl_xor(s, 2);
            s += __shfl_xor(s, 4); s += __shfl_xor(s, 8);
            if (lr == 0) ssq[w][rf * 16 + lq * 4 + r] = s;
        }
    __syncthreads();
    #pragma unroll
    for (int rf = 0; rf < 4; ++rf)
        #pragma unroll
        for (int r = 0; r < 4; ++r) {
            const int nl = rf * 16 + lq * 4 + r;
            const float tot = ssq[0][nl] + ssq[1][nl] + ssq[2][nl] + ssq[3][nl];
            const float inv = 1.f / (sqrtf(tot) * 0.0625f + 1e-8f);
            #pragma unroll
            for (int cf = 0; cf < 4; ++cf) {
                const int d = w * 64 + cf * 16 + lr;
                out[(n0 + nl) * 256 + d] = sc[cf] * acc[rf][cf][r] * inv;
            }
        }
}

// ---------------------------------------------------------------------------
extern "C" void kernel_launch(void* const* d_in, const int* in_sizes, int n_in,
                              void* d_out, int out_size, void* d_ws, size_t ws_size,
                              hipStream_t stream)
{
    const float* agent   = (const float*)d_in[0];
    const float* x       = (const float*)d_in[1];
    const float* W_qkv   = (const float*)d_in[2];
    const float* b_qkv   = (const float*)d_in[3];
    const float* W_agent = (const float*)d_in[4];
    const float* b_agent = (const float*)d_in[5];
    const float* W_fc1   = (const float*)d_in[6];
    const float* b_fc1   = (const float*)d_in[7];
    const float* W_fc2   = (const float*)d_in[8];
    const float* b_fc2   = (const float*)d_in[9];
    const float* nscale  = (const float*)d_in[10];
    float* out = (float*)d_out;

    char* wsp = (char*)d_ws;
    size_t off = 0;
    auto alloc = [&](size_t n) { void* p = wsp + off; off += (n + 255) & ~(size_t)255; return p; };

    float*  qa_out = (float*)alloc(64UL * 512 * 4);
    unsigned short* MS = (unsigned short*)alloc(128UL * 256 * 2);
    float*  cbias  = (float*)alloc(128UL * 4);
    float*  S1T    = (float*)alloc(65536UL * 64 * 4);   // [n][a]
    float*  S2     = (float*)alloc(65536UL * 64 * 4);   // [n][a]
    float*  mpart  = (float*)alloc(1024UL * 64 * 4);
    float*  lpart  = (float*)alloc(1024UL * 64 * 4);
    float*  m1     = (float*)alloc(512UL * 4);
    float*  l1inv  = (float*)alloc(512UL * 4);
    float*  y_part = (float*)alloc(8UL * 32 * 64 * 256 * 4);
    float*  y_raw  = (float*)alloc(512UL * 256 * 4);
    float*  t0     = (float*)alloc(512UL * 256 * 4);
    float*  t1     = (float*)alloc(512UL * 256 * 4);
    float*  uu     = (float*)alloc(512UL * 256 * 4);

    // 1. agent projection: [64][512] f32  (8 col-tile blocks)
    gemm_k256<true, true, false, true><<<dim3(1, 8, 1), 256, 0, stream>>>(
        agent, 256, 0, W_agent, 256, b_agent, qa_out, 512, 0, 64, 512);
    // 2. score matrices M1|M2 + bias consts
    build_M2<<<128, 256, 0, stream>>>(W_qkv, b_qkv, qa_out, MS, cbias);
    // 3. streaming scores S1T, S2 + stage-1 softmax partials
    xproj2<<<1024, 256, 0, stream>>>(x, MS, cbias, S1T, S2, mpart, lpart);
    // 4. combine stage-1 stats
    s1_combine<<<8, 256, 0, stream>>>(mpart, lpart, m1, l1inv);
    // 5. y = attn1 @ x via MFMA
    pv_mfma2<<<dim3(32, 2, 8), 256, 0, stream>>>(S1T, x, m1, l1inv, y_part);
    // 6. reduce partials
    v1_reduce<<<dim3(64, 8), 64, 0, stream>>>(y_part, y_raw);
    // 7. folded chain: u = ((y@Wv^T+bv)@W1^T+b1)@W2^T+b2
    gemm_k256<true, true, false, true><<<dim3(4, 4, 1), 256, 0, stream>>>(
        y_raw, 256, 0, W_qkv + 512 * 256, 256, b_qkv + 512, t0, 256, 0, 512, 256);
    gemm_k256<true, true, false, true><<<dim3(4, 4, 1), 256, 0, stream>>>(
        t0, 256, 0, W_fc1, 256, b_fc1, t1, 256, 0, 512, 256);
    gemm_k256<true, true, false, true><<<dim3(4, 4, 1), 256, 0, stream>>>(
        t1, 256, 0, W_fc2, 256, b_fc2, uu, 256, 0, 512, 256);
    // 8. softmax(64) + PV MFMA + residual + rmsnorm
    stage2_final<<<1024, 256, 0, stream>>>(S2, uu, x, nscale, out);
}

// Round 6
// 140.495 us; speedup vs baseline: 3.1044x; 1.0943x over previous
//
#include <hip/hip_runtime.h>
#include <hip/hip_bf16.h>

typedef __attribute__((ext_vector_type(4))) float f32x4;
typedef __attribute__((ext_vector_type(8))) short s16x8;
typedef __attribute__((ext_vector_type(4))) short s16x4;

__device__ __forceinline__ unsigned short f2bf(float f) {
    unsigned int u; __builtin_memcpy(&u, &f, 4);
    u += 0x7fffu + ((u >> 16) & 1u);
    return (unsigned short)(u >> 16);
}
__device__ __forceinline__ float bf2f(unsigned short h) {
    unsigned int u = ((unsigned int)h) << 16;
    float f; __builtin_memcpy(&f, &u, 4);
    return f;
}
__device__ __forceinline__ s16x8 pack8(f32x4 a, f32x4 b) {
    s16x8 r;
    r[0] = (short)f2bf(a[0]); r[1] = (short)f2bf(a[1]);
    r[2] = (short)f2bf(a[2]); r[3] = (short)f2bf(a[3]);
    r[4] = (short)f2bf(b[0]); r[5] = (short)f2bf(b[1]);
    r[6] = (short)f2bf(b[2]); r[7] = (short)f2bf(b[3]);
    return r;
}

// ---------------------------------------------------------------------------
// Generic C = A @ B^T (+bias) GEMM, K=256 — small matmuls (agent proj, chain).
// Each block handles one 64-col tile (nt = blockIdx.y) of 128 rows.
// ---------------------------------------------------------------------------
template<bool AF32, bool BF32, bool OUTBF16, bool BIAS>
__global__ __launch_bounds__(256) void gemm_k256(
    const void* __restrict__ Ap, long sA, long bAstr,
    const void* __restrict__ Bp, long sB,
    const float* __restrict__ bias,
    void* __restrict__ Cp, long sC, long bCstr,
    int M, int N)
{
    __shared__ alignas(16) unsigned short As[128 * 256];
    __shared__ alignas(16) unsigned short Bs[64 * 256];
    const int tid = threadIdx.x;
    const int lane = tid & 63;
    const int w = tid >> 6;
    const int m0 = blockIdx.x * 128;
    const int nt = blockIdx.y;
    const int z = blockIdx.z;

    {
        const int kk = (tid & 31) * 8;
        #pragma unroll
        for (int j = 0; j < 16; ++j) {
            const int row = (tid >> 5) + j * 8;
            int rowg = m0 + row; if (rowg > M - 1) rowg = M - 1;
            s16x8 v;
            if constexpr (AF32) {
                const float* s = (const float*)Ap + (size_t)z * bAstr + (size_t)rowg * sA + kk;
                f32x4 f0 = *(const f32x4*)s;
                f32x4 f1 = *(const f32x4*)(s + 4);
                v = pack8(f0, f1);
            } else {
                const unsigned short* s = (const unsigned short*)Ap + (size_t)z * bAstr + (size_t)rowg * sA + kk;
                v = *(const s16x8*)s;
            }
            *(s16x8*)((char*)As + row * 512 + ((kk * 2) ^ ((row & 7) << 4))) = v;
        }
        #pragma unroll
        for (int j = 0; j < 8; ++j) {
            const int row = (tid >> 5) + j * 8;
            const int rowg = nt * 64 + row;
            s16x8 v;
            if constexpr (BF32) {
                const float* s = (const float*)Bp + (size_t)rowg * sB + kk;
                f32x4 f0 = *(const f32x4*)s;
                f32x4 f1 = *(const f32x4*)(s + 4);
                v = pack8(f0, f1);
            } else {
                const unsigned short* s = (const unsigned short*)Bp + (size_t)rowg * sB + kk;
                v = *(const s16x8*)s;
            }
            *(s16x8*)((char*)Bs + row * 512 + ((kk * 2) ^ ((row & 7) << 4))) = v;
        }
    }
    __syncthreads();

    f32x4 acc[2][4];
    const f32x4 zero = {0.f, 0.f, 0.f, 0.f};
    #pragma unroll
    for (int rf = 0; rf < 2; ++rf)
        #pragma unroll
        for (int cf = 0; cf < 4; ++cf)
            acc[rf][cf] = zero;

    #pragma unroll
    for (int ks = 0; ks < 8; ++ks) {
        const int kb = ks * 64 + ((lane >> 4) << 4);
        s16x8 areg[2], bfr[4];
        #pragma unroll
        for (int rf = 0; rf < 2; ++rf) {
            const int row = w * 32 + rf * 16 + (lane & 15);
            areg[rf] = *(const s16x8*)((const char*)As + row * 512 + (kb ^ ((row & 7) << 4)));
        }
        #pragma unroll
        for (int cf = 0; cf < 4; ++cf) {
            const int row = cf * 16 + (lane & 15);
            bfr[cf] = *(const s16x8*)((const char*)Bs + row * 512 + (kb ^ ((row & 7) << 4)));
        }
        #pragma unroll
        for (int rf = 0; rf < 2; ++rf)
            #pragma unroll
            for (int cf = 0; cf < 4; ++cf)
                acc[rf][cf] = __builtin_amdgcn_mfma_f32_16x16x32_bf16(
                    areg[rf], bfr[cf], acc[rf][cf], 0, 0, 0);
    }

    #pragma unroll
    for (int cf = 0; cf < 4; ++cf) {
        const int n = nt * 64 + cf * 16 + (lane & 15);
        const float bv = BIAS ? bias[n] : 0.f;
        #pragma unroll
        for (int rf = 0; rf < 2; ++rf) {
            #pragma unroll
            for (int r = 0; r < 4; ++r) {
                const int m = m0 + w * 32 + rf * 16 + ((lane >> 4) << 2) + r;
                if (m < M) {
                    const float v = acc[rf][cf][r] + bv;
                    const size_t co = (size_t)z * bCstr + (size_t)m * sC + n;
                    if constexpr (OUTBF16) ((unsigned short*)Cp)[co] = f2bf(v);
                    else                   ((float*)Cp)[co] = v;
                }
            }
        }
    }
}

// ---------------------------------------------------------------------------
// Build MS [128][256] bf16 + cbias[128]:
//   rows  0..63 : M1[a] = qa_s @ W_k  (cbias = b_k . qa_s[a])   [stage-1]
//   rows 64..127: M2[a] = ka_s @ W_q  (cbias = b_q . ka_s[a])   [stage-2]
// ---------------------------------------------------------------------------
__global__ __launch_bounds__(256) void build_M2(
    const float* __restrict__ W_qkv, const float* __restrict__ b_qkv,
    const float* __restrict__ qa_out,
    unsigned short* __restrict__ MS, float* __restrict__ cbias)
{
    const int i = blockIdx.x;  // 0..127
    const int t = threadIdx.x;
    __shared__ float qs[256];
    const int a = i & 63;
    const bool isS1 = (i < 64);
    qs[t] = qa_out[(size_t)a * 512 + (isS1 ? t : 256 + t)] * 0.0625f;
    __syncthreads();
    const float* W  = W_qkv + (isS1 ? 256 * 256 : 0);   // W_k : W_q
    const float* bb = b_qkv + (isS1 ? 256 : 0);
    float acc = 0.f, cb = 0.f;
    for (int dout = 0; dout < 256; ++dout) {
        const float q = qs[dout];
        acc += q * W[(size_t)dout * 256 + t];
        cb  += q * bb[dout];
    }
    MS[i * 256 + t] = f2bf(acc);
    if (t == 0) cbias[i] = cb;
}

// ---------------------------------------------------------------------------
// Streaming scores: per 64-token block computes S1T[n][a], S2[n][a] (f32)
// and stage-1 softmax partials.
// ---------------------------------------------------------------------------
__global__ __launch_bounds__(256) void xproj2(
    const float* __restrict__ x,
    const unsigned short* __restrict__ MS,
    const float* __restrict__ cbias,
    float* __restrict__ S1T,
    float* __restrict__ S2,
    float* __restrict__ mpart, float* __restrict__ lpart)
{
    __shared__ alignas(16) unsigned short As[64 * 256];   // 32KB
    const int tid = threadIdx.x, lane = tid & 63, w = tid >> 6;
    const int lr = lane & 15, lq = lane >> 4;
    const long m0 = (long)blockIdx.x * 64;

    {
        const int k0 = (tid & 31) * 8;
        #pragma unroll
        for (int j = 0; j < 8; ++j) {
            const int row = (tid >> 5) + j * 8;
            const float* s = x + (m0 + row) * 256 + k0;
            f32x4 f0 = *(const f32x4*)s;
            f32x4 f1 = *(const f32x4*)(s + 4);
            *(s16x8*)((char*)As + row * 512 + ((k0 * 2) ^ ((row & 7) << 4))) = pack8(f0, f1);
        }
    }
    __syncthreads();

    f32x4 acc[4][2];
    const f32x4 zero = {0.f, 0.f, 0.f, 0.f};
    #pragma unroll
    for (int rf = 0; rf < 4; ++rf)
        #pragma unroll
        for (int j = 0; j < 2; ++j)
            acc[rf][j] = zero;

    #pragma unroll
    for (int ks = 0; ks < 8; ++ks) {
        const int kb = ks * 64 + lq * 16;
        s16x8 areg[4];
        #pragma unroll
        for (int rf = 0; rf < 4; ++rf) {
            const int row = rf * 16 + lr;
            areg[rf] = *(const s16x8*)((const char*)As + row * 512 + (kb ^ ((row & 7) << 4)));
        }
        s16x8 bfr[2];
        #pragma unroll
        for (int j = 0; j < 2; ++j) {
            const int msrow = j * 64 + w * 16 + lr;
            bfr[j] = *(const s16x8*)((const char*)MS + (size_t)msrow * 512 + kb);
        }
        #pragma unroll
        for (int rf = 0; rf < 4; ++rf)
            #pragma unroll
            for (int j = 0; j < 2; ++j)
                acc[rf][j] = __builtin_amdgcn_mfma_f32_16x16x32_bf16(
                    areg[rf], bfr[j], acc[rf][j], 0, 0, 0);
    }

    #pragma unroll
    for (int j = 0; j < 2; ++j) {
        const int a = w * 16 + lr;
        const float bv = cbias[j * 64 + a];
        float* dst = j ? S2 : S1T;
        float mx = -1e30f;
        #pragma unroll
        for (int rf = 0; rf < 4; ++rf)
            #pragma unroll
            for (int r = 0; r < 4; ++r) {
                const float v = acc[rf][j][r] + bv;
                dst[(m0 + rf * 16 + lq * 4 + r) * 64 + a] = v;
                mx = fmaxf(mx, v);
            }
        if (j == 0) {
            mx = fmaxf(mx, __shfl_xor(mx, 16));
            mx = fmaxf(mx, __shfl_xor(mx, 32));
            float sm = 0.f;
            #pragma unroll
            for (int rf = 0; rf < 4; ++rf)
                #pragma unroll
                for (int r = 0; r < 4; ++r)
                    sm += __expf(acc[rf][j][r] + bv - mx);
            sm += __shfl_xor(sm, 16);
            sm += __shfl_xor(sm, 32);
            if (lq == 0) {
                mpart[(size_t)blockIdx.x * 64 + a] = mx;
                lpart[(size_t)blockIdx.x * 64 + a] = sm;
            }
        }
    }
}

// ---------------------------------------------------------------------------
// Combine stage-1 partials (128 chunks of 64 tokens per batch).
// ---------------------------------------------------------------------------
__global__ __launch_bounds__(256) void s1_combine(const float* __restrict__ mpart,
                                                  const float* __restrict__ lpart,
                                                  float* __restrict__ m1,
                                                  float* __restrict__ l1inv)
{
    const int b = blockIdx.x;
    const int a = threadIdx.x & 63, s = threadIdx.x >> 6;
    float M = -1e30f;
    for (int c = s; c < 128; c += 4)
        M = fmaxf(M, mpart[((size_t)b * 128 + c) * 64 + a]);
    float L = 0.f;
    for (int c = s; c < 128; c += 4) {
        const size_t idx = ((size_t)b * 128 + c) * 64 + a;
        L += lpart[idx] * __expf(mpart[idx] - M);
    }
    __shared__ float ms[256], ls[256];
    ms[threadIdx.x] = M; ls[threadIdx.x] = L;
    __syncthreads();
    if (threadIdx.x < 64) {
        const int aa = threadIdx.x;
        float Mm = ms[aa];
        #pragma unroll
        for (int ss = 1; ss < 4; ++ss) Mm = fmaxf(Mm, ms[ss * 64 + aa]);
        float Ll = 0.f;
        #pragma unroll
        for (int ss = 0; ss < 4; ++ss) Ll += ls[ss * 64 + aa] * __expf(ms[ss * 64 + aa] - Mm);
        m1[b * 64 + aa] = Mm;
        l1inv[b * 64 + aa] = 1.0f / Ll;
    }
}

// ---------------------------------------------------------------------------
// y = attn1 @ x via MFMA (partials over 32 n-chunks of 256).
// ---------------------------------------------------------------------------
__global__ __launch_bounds__(256) void pv_mfma2(
    const float* __restrict__ S1T,
    const float* __restrict__ x,
    const float* __restrict__ m1,
    const float* __restrict__ l1inv,
    float* __restrict__ y_part)
{
    __shared__ alignas(16) unsigned short P_lds[64 * 128];   // [a][n] 16KB
    __shared__ alignas(16) unsigned short XT[128 * 136];     // [d][136n] (pad row)
    const int tid = threadIdx.x, lane = tid & 63, w = tid >> 6;
    const int lr = lane & 15, lq = lane >> 4;
    const int c = blockIdx.x, dh = blockIdx.y, b = blockIdx.z;

    const int a4 = (tid & 15) * 4;
    const f32x4 m4 = *(const f32x4*)&m1[b * 64 + a4];
    const f32x4 l4 = *(const f32x4*)&l1inv[b * 64 + a4];

    f32x4 acc[4][2];
    const f32x4 zero = {0.f, 0.f, 0.f, 0.f};
    #pragma unroll
    for (int rf = 0; rf < 4; ++rf)
        #pragma unroll
        for (int cf = 0; cf < 2; ++cf)
            acc[rf][cf] = zero;

    for (int kt = 0; kt < 2; ++kt) {
        const size_t ng0 = (size_t)b * 8192 + c * 256 + kt * 128;
        #pragma unroll
        for (int pass = 0; pass < 4; ++pass) {
            const int np = 2 * (tid >> 4) + pass * 32;
            const float* s = S1T + (ng0 + np) * 64 + a4;
            f32x4 s0 = *(const f32x4*)s;
            f32x4 s1 = *(const f32x4*)(s + 64);
            #pragma unroll
            for (int j = 0; j < 4; ++j) {
                const int a = a4 + j;
                const float p0 = __expf(s0[j] - m4[j]) * l4[j];
                const float p1 = __expf(s1[j] - m4[j]) * l4[j];
                const unsigned int pk = (unsigned int)f2bf(p0) | ((unsigned int)f2bf(p1) << 16);
                *(unsigned int*)((char*)P_lds + a * 256 + ((np * 2) ^ (((a >> 1) & 7) << 4))) = pk;
            }
        }
        {
            const int nh = tid >> 2;
            const int dq = tid & 3;
            const float* xbase = x + (ng0 + 2 * nh) * 256 + dh * 128;
            #pragma unroll
            for (int pass = 0; pass < 8; ++pass) {
                const int dl0 = pass * 16 + dq * 4;
                f32x4 xa = *(const f32x4*)(xbase + dl0);
                f32x4 xb = *(const f32x4*)(xbase + 256 + dl0);
                #pragma unroll
                for (int jj = 0; jj < 4; ++jj) {
                    const unsigned int pk = (unsigned int)f2bf(xa[jj]) | ((unsigned int)f2bf(xb[jj]) << 16);
                    *(unsigned int*)((char*)XT + (dl0 + jj) * 272 + nh * 4) = pk;
                }
            }
        }
        __syncthreads();
        #pragma unroll
        for (int ks = 0; ks < 4; ++ks) {
            const int kbn = ks * 64 + lq * 16;
            s16x8 af[4], bfv[2];
            #pragma unroll
            for (int rf = 0; rf < 4; ++rf) {
                const int row = rf * 16 + lr;
                af[rf] = *(const s16x8*)((const char*)P_lds + row * 256 + (kbn ^ (((row >> 1) & 7) << 4)));
            }
            #pragma unroll
            for (int cf = 0; cf < 2; ++cf) {
                const int dl = w * 32 + cf * 16 + lr;
                bfv[cf] = *(const s16x8*)((const char*)XT + dl * 272 + kbn);
            }
            #pragma unroll
            for (int rf = 0; rf < 4; ++rf)
                #pragma unroll
                for (int cf = 0; cf < 2; ++cf)
                    acc[rf][cf] = __builtin_amdgcn_mfma_f32_16x16x32_bf16(
                        af[rf], bfv[cf], acc[rf][cf], 0, 0, 0);
        }
        __syncthreads();
    }
    #pragma unroll
    for (int rf = 0; rf < 4; ++rf)
        #pragma unroll
        for (int cf = 0; cf < 2; ++cf)
            #pragma unroll
            for (int r = 0; r < 4; ++r) {
                const int a = rf * 16 + lq * 4 + r;
                const int d = dh * 128 + w * 32 + cf * 16 + lr;
                y_part[(((size_t)b * 32 + c) * 64 + a) * 256 + d] = acc[rf][cf][r];
            }
}

__global__ void v1_reduce(const float* __restrict__ y_part,
                          float* __restrict__ y_raw)
{
    const int a = blockIdx.x, b = blockIdx.y, t = threadIdx.x;  // 64 thr
    f32x4 s = {0.f, 0.f, 0.f, 0.f};
    for (int c = 0; c < 32; ++c)
        s += *(const f32x4*)&y_part[(((size_t)b * 32 + c) * 64 + a) * 256 + t * 4];
    *(f32x4*)&y_raw[((size_t)b * 64 + a) * 256 + t * 4] = s;
}

// ---------------------------------------------------------------------------
// Stage-2 fused: parallel softmax(64) + PV via MFMA (A = uT rows d, B = P
// rows n -> thread holds 4 CONSECUTIVE d per token) + residual + RMSNorm,
// all f32x4 on the global hot path.
// ---------------------------------------------------------------------------
__global__ __launch_bounds__(256) void stage2_final(const float* __restrict__ S2,
                                                    const float* __restrict__ uu,
                                                    const float* __restrict__ x,
                                                    const float* __restrict__ nscale,
                                                    float* __restrict__ out)
{
    __shared__ alignas(16) unsigned short uT[256 * 64];  // [d][a] pitch 128B, swz
    __shared__ alignas(16) unsigned short P[64 * 64];    // [n][a] pitch 128B, swz
    __shared__ float ssq[4][64];
    const int tid = threadIdx.x, lane = tid & 63, w = tid >> 6;
    const int lr = lane & 15, lq = lane >> 4;
    const int b = blockIdx.x >> 7;
    const long n0 = (long)blockIdx.x * 64;

    // ---- stage uT[d][a] bf16 from uu[b][a][d] f32 (pair-packed transpose) ----
    {
        const int pr = tid >> 3;      // a-pair 0..31
        const int sub = tid & 7;
        const float* u0 = uu + ((size_t)b * 64 + 2 * pr) * 256;
        #pragma unroll
        for (int pass = 0; pass < 8; ++pass) {
            const int d0 = pass * 32 + sub * 4;
            f32x4 ua = *(const f32x4*)(u0 + d0);
            f32x4 ub = *(const f32x4*)(u0 + 256 + d0);
            #pragma unroll
            for (int jj = 0; jj < 4; ++jj) {
                const int d = d0 + jj;
                const unsigned int pk = (unsigned int)f2bf(ua[jj]) | ((unsigned int)f2bf(ub[jj]) << 16);
                *(unsigned int*)((char*)uT + d * 128 + ((pr * 4) ^ ((d & 7) << 4))) = pk;
            }
        }
    }
    // ---- parallel softmax: 4-lane group per token, 16 tokens/wave at once ----
    {
        const int t = lane >> 2, q = lane & 3;
        const int nl = w * 16 + t;
        const float* srow = S2 + (n0 + nl) * 64 + q * 16;
        f32x4 sv[4];
        #pragma unroll
        for (int j = 0; j < 4; ++j) sv[j] = *(const f32x4*)(srow + j * 4);
        float mx = -1e30f;
        #pragma unroll
        for (int j = 0; j < 4; ++j)
            #pragma unroll
            for (int e = 0; e < 4; ++e) mx = fmaxf(mx, sv[j][e]);
        mx = fmaxf(mx, __shfl_xor(mx, 1));
        mx = fmaxf(mx, __shfl_xor(mx, 2));
        float p[16];
        float sm = 0.f;
        #pragma unroll
        for (int j = 0; j < 4; ++j)
            #pragma unroll
            for (int e = 0; e < 4; ++e) {
                p[j * 4 + e] = __expf(sv[j][e] - mx);
                sm += p[j * 4 + e];
            }
        sm += __shfl_xor(sm, 1);
        sm += __shfl_xor(sm, 2);
        const float rs = 1.f / sm;
        s16x8 o0, o1;
        #pragma unroll
        for (int e = 0; e < 8; ++e) o0[e] = (short)f2bf(p[e] * rs);
        #pragma unroll
        for (int e = 0; e < 8; ++e) o1[e] = (short)f2bf(p[8 + e] * rs);
        const int swz = (nl & 7) << 4;
        *(s16x8*)((char*)P + nl * 128 + ((q * 32) ^ swz)) = o0;
        *(s16x8*)((char*)P + nl * 128 + ((q * 32 + 16) ^ swz)) = o1;
    }
    __syncthreads();

    // ---- PV MFMA: A = uT rows (d), B = P rows (n) -> C[d][n] ----
    f32x4 acc[4][4];
    const f32x4 zero = {0.f, 0.f, 0.f, 0.f};
    #pragma unroll
    for (int rf = 0; rf < 4; ++rf)
        #pragma unroll
        for (int cf = 0; cf < 4; ++cf)
            acc[rf][cf] = zero;
    #pragma unroll
    for (int ks = 0; ks < 2; ++ks) {
        const int kb = ks * 64 + lq * 16;
        s16x8 af[4], bfv[4];
        #pragma unroll
        for (int rf = 0; rf < 4; ++rf) {
            const int dR = w * 64 + rf * 16 + lr;
            af[rf] = *(const s16x8*)((const char*)uT + dR * 128 + (kb ^ ((dR & 7) << 4)));
        }
        #pragma unroll
        for (int cf = 0; cf < 4; ++cf) {
            const int nR = cf * 16 + lr;
            bfv[cf] = *(const s16x8*)((const char*)P + nR * 128 + (kb ^ ((nR & 7) << 4)));
        }
        #pragma unroll
        for (int rf = 0; rf < 4; ++rf)
            #pragma unroll
            for (int cf = 0; cf < 4; ++cf)
                acc[rf][cf] = __builtin_amdgcn_mfma_f32_16x16x32_bf16(
                    af[rf], bfv[cf], acc[rf][cf], 0, 0, 0);
    }

    // ---- residual (f32x4) + per-token partial ssq ----
    float part[4] = {0.f, 0.f, 0.f, 0.f};
    #pragma unroll
    for (int cf = 0; cf < 4; ++cf) {
        const long n = n0 + cf * 16 + lr;
        #pragma unroll
        for (int rf = 0; rf < 4; ++rf) {
            const int d0 = w * 64 + rf * 16 + lq * 4;
            const f32x4 xr = *(const f32x4*)&x[n * 256 + d0];
            acc[rf][cf] += xr;
            part[cf] += acc[rf][cf][0] * acc[rf][cf][0] + acc[rf][cf][1] * acc[rf][cf][1]
                      + acc[rf][cf][2] * acc[rf][cf][2] + acc[rf][cf][3] * acc[rf][cf][3];
        }
    }
    #pragma unroll
    for (int cf = 0; cf < 4; ++cf) {
        float s = part[cf];
        s += __shfl_xor(s, 16);
        s += __shfl_xor(s, 32);
        if (lq == 0) ssq[w][cf * 16 + lr] = s;
    }
    __syncthreads();

    // ---- rmsnorm + store (f32x4) ----
    #pragma unroll
    for (int cf = 0; cf < 4; ++cf) {
        const int tokl = cf * 16 + lr;
        const float tot = ssq[0][tokl] + ssq[1][tokl] + ssq[2][tokl] + ssq[3][tokl];
        const float inv = 1.f / (sqrtf(tot) * 0.0625f + 1e-8f);
        const long n = n0 + tokl;
        #pragma unroll
        for (int rf = 0; rf < 4; ++rf) {
            const int d0 = w * 64 + rf * 16 + lq * 4;
            const f32x4 sc4 = *(const f32x4*)&nscale[d0];
            f32x4 o = sc4 * acc[rf][cf] * inv;
            *(f32x4*)&out[n * 256 + d0] = o;
        }
    }
}

// ---------------------------------------------------------------------------
extern "C" void kernel_launch(void* const* d_in, const int* in_sizes, int n_in,
                              void* d_out, int out_size, void* d_ws, size_t ws_size,
                              hipStream_t stream)
{
    const float* agent   = (const float*)d_in[0];
    const float* x       = (const float*)d_in[1];
    const float* W_qkv   = (const float*)d_in[2];
    const float* b_qkv   = (const float*)d_in[3];
    const float* W_agent = (const float*)d_in[4];
    const float* b_agent = (const float*)d_in[5];
    const float* W_fc1   = (const float*)d_in[6];
    const float* b_fc1   = (const float*)d_in[7];
    const float* W_fc2   = (const float*)d_in[8];
    const float* b_fc2   = (const float*)d_in[9];
    const float* nscale  = (const float*)d_in[10];
    float* out = (float*)d_out;

    char* wsp = (char*)d_ws;
    size_t off = 0;
    auto alloc = [&](size_t n) { void* p = wsp + off; off += (n + 255) & ~(size_t)255; return p; };

    float*  qa_out = (float*)alloc(64UL * 512 * 4);
    unsigned short* MS = (unsigned short*)alloc(128UL * 256 * 2);
    float*  cbias  = (float*)alloc(128UL * 4);
    float*  S1T    = (float*)alloc(65536UL * 64 * 4);   // [n][a]
    float*  S2     = (float*)alloc(65536UL * 64 * 4);   // [n][a]
    float*  mpart  = (float*)alloc(1024UL * 64 * 4);
    float*  lpart  = (float*)alloc(1024UL * 64 * 4);
    float*  m1     = (float*)alloc(512UL * 4);
    float*  l1inv  = (float*)alloc(512UL * 4);
    float*  y_part = (float*)alloc(8UL * 32 * 64 * 256 * 4);
    float*  y_raw  = (float*)alloc(512UL * 256 * 4);
    float*  t0     = (float*)alloc(512UL * 256 * 4);
    float*  t1     = (float*)alloc(512UL * 256 * 4);
    float*  uu     = (float*)alloc(512UL * 256 * 4);

    // 1. agent projection: [64][512] f32  (8 col-tile blocks)
    gemm_k256<true, true, false, true><<<dim3(1, 8, 1), 256, 0, stream>>>(
        agent, 256, 0, W_agent, 256, b_agent, qa_out, 512, 0, 64, 512);
    // 2. score matrices M1|M2 + bias consts
    build_M2<<<128, 256, 0, stream>>>(W_qkv, b_qkv, qa_out, MS, cbias);
    // 3. streaming scores S1T, S2 + stage-1 softmax partials
    xproj2<<<1024, 256, 0, stream>>>(x, MS, cbias, S1T, S2, mpart, lpart);
    // 4. combine stage-1 stats
    s1_combine<<<8, 256, 0, stream>>>(mpart, lpart, m1, l1inv);
    // 5. y = attn1 @ x via MFMA
    pv_mfma2<<<dim3(32, 2, 8), 256, 0, stream>>>(S1T, x, m1, l1inv, y_part);
    // 6. reduce partials
    v1_reduce<<<dim3(64, 8), 64, 0, stream>>>(y_part, y_raw);
    // 7. folded chain: u = ((y@Wv^T+bv)@W1^T+b1)@W2^T+b2
    gemm_k256<true, true, false, true><<<dim3(4, 4, 1), 256, 0, stream>>>(
        y_raw, 256, 0, W_qkv + 512 * 256, 256, b_qkv + 512, t0, 256, 0, 512, 256);
    gemm_k256<true, true, false, true><<<dim3(4, 4, 1), 256, 0, stream>>>(
        t0, 256, 0, W_fc1, 256, b_fc1, t1, 256, 0, 512, 256);
    gemm_k256<true, true, false, true><<<dim3(4, 4, 1), 256, 0, stream>>>(
        t1, 256, 0, W_fc2, 256, b_fc2, uu, 256, 0, 512, 256);
    // 8. parallel softmax + PV MFMA + residual + rmsnorm
    stage2_final<<<1024, 256, 0, stream>>>(S2, uu, x, nscale, out);
}